// Round 3
// baseline (588.528 us; speedup 1.0000x reference)
//
#include <hip/hip_runtime.h>
#include <math.h>

#define D      256
#define K      16384
#define NPTS   8192
#define DELTA  0.2f
#define LCAP   256
#define MAXCAP 4000000u

// d_out layout (all f32): zq[8,256,32,32] | indices[8192] | bit[8,32,32,256] | loss[1]
#define O_IDX  2097152
#define O_BIT  2105344
#define O_LOSS 4202496

typedef __attribute__((ext_vector_type(8))) short bf16x8;
typedef __attribute__((ext_vector_type(4))) float f32x4;
typedef unsigned long long u64;

__device__ __forceinline__ unsigned f2s(float f) {
    unsigned u = __float_as_uint(f);
    return (u & 0x80000000u) ? ~u : (u | 0x80000000u);
}
__device__ __forceinline__ float s2f(unsigned s) {
    return __uint_as_float((s & 0x80000000u) ? (s & 0x7fffffffu) : ~s);
}
__device__ __forceinline__ unsigned short f2bf(float f) {  // RNE
    unsigned u = __float_as_uint(f);
    u += 0x7fffu + ((u >> 16) & 1u);
    return (unsigned short)(u >> 16);
}

// async global->LDS, 16B per lane (wave-uniform base + lane*16 dest)
__device__ __forceinline__ void gload16(const unsigned short* g, unsigned short* l) {
    __builtin_amdgcn_global_load_lds(
        (const __attribute__((address_space(1))) unsigned int*)g,
        (__attribute__((address_space(3))) unsigned int*)l, 16, 0, 0);
}

// k-major fragment layouts: X[(k>>3)][row][8] bf16, 16B per (row, k-chunk)
//   zfbT: [32][NPTS][8] bf16 ; ewbT: [32][K][8] bf16

// ---- merged prep: blocks [0,512) codebook; [512,640) z transpose; state init folded ----
__global__ __launch_bounds__(256) void prep(const float* __restrict__ E,
                                            const float* __restrict__ z,
                                            float* __restrict__ den,
                                            unsigned short* __restrict__ ewbT,
                                            unsigned short* __restrict__ zfbT,
                                            float* __restrict__ zf32,
                                            unsigned* __restrict__ gmax,
                                            u64* __restrict__ keys,
                                            unsigned* __restrict__ cnt) {
    const int blk = blockIdx.x, tid = threadIdx.x;
    if (blk < 512) {
        const int lane = tid & 63, wave = tid >> 6;
        if (blk < 32)        gmax[blk * 256 + tid] = 0u;
        else if (blk < 64)   keys[(blk - 32) * 256 + tid] = 0ull;
        else if (blk == 64 && tid < 2) cnt[tid] = 0u;
        #pragma unroll
        for (int j = 0; j < 8; ++j) {
            const int row = blk * 32 + wave * 8 + j;
            const float4 v = *(const float4*)(E + (size_t)row * D + lane * 4);
            float ss = v.x * v.x + v.y * v.y + v.z * v.z + v.w * v.w;
            #pragma unroll
            for (int o = 1; o < 64; o <<= 1) ss += __shfl_xor(ss, o);
            const float dn = fmaxf(sqrtf(ss), 1e-12f);
            const unsigned lo = (unsigned)f2bf(v.x / dn) | ((unsigned)f2bf(v.y / dn) << 16);
            const unsigned hi = (unsigned)f2bf(v.z / dn) | ((unsigned)f2bf(v.w / dn) << 16);
            // k = lane*4 .. +4 -> chunk lane>>1, offset (lane&1)*4
            *(uint2*)(ewbT + ((size_t)(lane >> 1) * K + row) * 8 + (lane & 1) * 4)
                = make_uint2(lo, hi);
            if (lane == 0) den[row] = dn;
        }
    } else {
        const int bi = blk - 512;
        const int b = bi >> 4, hw0 = (bi & 15) * 64;
        __shared__ float t[64][65];
        for (int dc = 0; dc < D; dc += 64) {
            #pragma unroll
            for (int it = 0; it < 16; ++it) {
                const int idx = it * 256 + tid;
                const int dl = idx >> 6, hw = idx & 63;
                t[dl][hw] = z[(size_t)(b * 256 + dc + dl) * 1024 + hw0 + hw];
            }
            __syncthreads();
            #pragma unroll
            for (int it = 0; it < 16; ++it) {
                const int idx = it * 256 + tid;
                const int pl = idx >> 6, dl = idx & 63;
                const float v = t[dl][pl];
                const int p = b * 1024 + hw0 + pl, k = dc + dl;
                zfbT[((size_t)(k >> 3) * NPTS + p) * 8 + (k & 7)] = f2bf(v);
                zf32[(size_t)p * D + k] = v;
            }
            __syncthreads();
        }
    }
}

// ================= pipelined GEMM core (T3+T4+T5: counted vmcnt, never 0 in-loop) =================
// 4 waves, 2x2 wave grid, tile 128m x 128n, BK=32, 8 K-steps, 3 LDS buffers, depth-2 prefetch.
// Per step: s_waitcnt vmcnt(4) -> s_barrier -> STAGE(t+2) -> COMPUTE(t). Loads for 2 tiles
// stay in flight across barriers. Only the final step drains vmcnt(0).
// LDS cell order permuted on the GLOBAL side (source row pp ^ (q<<1)) so fragment
// ds_read_b128s land 2-way per bank-group (free); reads undo the XOR.

#define STAGE(buf, t)                                                               \
    do {                                                                            \
        const size_t oA_ = (size_t)(t) * (4 * NPTS * 8);                            \
        const size_t oB_ = (size_t)(t) * (4 * K * 8);                               \
        gload16(gA0_ + oA_, &sA[buf][tid * 8]);                                     \
        gload16(gA1_ + oA_, &sA[buf][2048 + tid * 8]);                              \
        gload16(gB0_ + oB_, &sB[buf][tid * 8]);                                     \
        gload16(gB1_ + oB_, &sB[buf][2048 + tid * 8]);                              \
    } while (0)

#define COMPUTE(buf)                                                                \
    do {                                                                            \
        bf16x8 af_[4], bf_[4];                                                      \
        const unsigned short* a_ = &sA[buf][(size_t)sbA_ * 8];                      \
        const unsigned short* b_ = &sB[buf][(size_t)sbB_ * 8];                      \
        _Pragma("unroll")                                                           \
        for (int mt = 0; mt < 4; ++mt) {                                            \
            af_[mt] = *(const bf16x8*)(a_ + mt * 128);                              \
            bf_[mt] = *(const bf16x8*)(b_ + mt * 128);                              \
        }                                                                           \
        __builtin_amdgcn_s_setprio(1);                                              \
        _Pragma("unroll")                                                           \
        for (int mt = 0; mt < 4; ++mt)                                              \
            _Pragma("unroll")                                                       \
            for (int nt = 0; nt < 4; ++nt)                                          \
                acc[mt][nt] = __builtin_amdgcn_mfma_f32_16x16x32_bf16(af_[mt], bf_[nt], \
                                                                      acc[mt][nt], 0, 0, 0); \
        __builtin_amdgcn_s_setprio(0);                                              \
    } while (0)

// wait for own loads down to VM outstanding, then execution-barrier. The trailing empty
// memory-clobber asm keeps the compiler from hoisting the COMPUTE ds_reads above the barrier.
#define WAITBAR(VM)                                                                 \
    asm volatile("s_waitcnt vmcnt(" VM ")" ::: "memory");                           \
    __builtin_amdgcn_s_barrier();                                                   \
    asm volatile("" ::: "memory");

#define GEMM_CORE()                                                                 \
    __shared__ unsigned short sA[3][4096];                                          \
    __shared__ unsigned short sB[3][4096];                                          \
    f32x4 acc[4][4];                                                                \
    _Pragma("unroll")                                                               \
    for (int i_ = 0; i_ < 4; ++i_)                                                  \
        _Pragma("unroll")                                                           \
        for (int j_ = 0; j_ < 4; ++j_) acc[i_][j_] = (f32x4){0.f, 0.f, 0.f, 0.f};   \
    const int q0_ = tid >> 7, q1_ = q0_ + 2, pp_ = tid & 127;                       \
    const unsigned short* gA0_ = zfbT + ((size_t)q0_ * NPTS + m0 + (pp_ ^ (q0_ << 1))) * 8; \
    const unsigned short* gA1_ = zfbT + ((size_t)q1_ * NPTS + m0 + (pp_ ^ (q1_ << 1))) * 8; \
    const unsigned short* gB0_ = ewbT + ((size_t)q0_ * K + n0 + (pp_ ^ (q0_ << 1))) * 8; \
    const unsigned short* gB1_ = ewbT + ((size_t)q1_ * K + n0 + (pp_ ^ (q1_ << 1))) * 8; \
    const int sbA_ = quad * 128 + ((wm * 64 + col) ^ (quad << 1));                  \
    const int sbB_ = quad * 128 + ((wn * 64 + col) ^ (quad << 1));                  \
    STAGE(0, 0);                                                                    \
    STAGE(1, 1);                                                                    \
    WAITBAR("4") STAGE(2, 2); COMPUTE(0);                                           \
    WAITBAR("4") STAGE(0, 3); COMPUTE(1);                                           \
    WAITBAR("4") STAGE(1, 4); COMPUTE(2);                                           \
    WAITBAR("4") STAGE(2, 5); COMPUTE(0 + 0); /* buf 3%3=0 */                       \
    WAITBAR("4") STAGE(0, 6); COMPUTE(1);     /* buf 4%3=1 */                       \
    WAITBAR("4") STAGE(1, 7); COMPUTE(2);     /* buf 5%3=2 */                       \
    WAITBAR("4")              COMPUTE(0);     /* buf 6%3=0 */                       \
    WAITBAR("0")              COMPUTE(1);     /* buf 7%3=1 */

// XCD-chunked bijective remap (T1). Default assignment is round-robin by linear id
// (xcd = lin % 8). We give XCD k the m-tile chunk [8k, 8k+8) and walk n-slices in
// order: per-XCD zfbT footprint = 512 KB (L2-resident, reused across all slices);
// each 64 KB ewbT slice is fetched into the XCD's L2 once and shared by the ~8
// concurrently-resident m-blocks. Valid since grid totals (1024, 7168) are % 8 == 0.
#define XCD_REMAP()                                                                 \
    const unsigned lin_ = blockIdx.x + 64u * blockIdx.y;                            \
    const unsigned j_ = lin_ >> 3;                                                  \
    const int mtile_ = (int)(((lin_ & 7u) << 3) | (j_ & 7u));                       \
    const int ntile_ = (int)(j_ >> 3);

// ---- phase 1: slices [0,16). Self-seeded thresholds; publishes block max at exit. ----
__global__ __launch_bounds__(256, 3) void score_seed(const unsigned short* __restrict__ zfbT,
                                                     const unsigned short* __restrict__ ewbT,
                                                     unsigned* __restrict__ gmax,
                                                     u64* __restrict__ cand,
                                                     unsigned* __restrict__ cnt,
                                                     unsigned cap) {
    __shared__ unsigned thrS[128];
    __shared__ u64 lbuf[LCAP];
    __shared__ unsigned lcount, lbase;

    const int tid = threadIdx.x, lane = tid & 63, wave = tid >> 6;
    const int quad = lane >> 4, col = lane & 15;
    const int wm = wave >> 1, wn = wave & 1;
    XCD_REMAP()
    const int m0 = mtile_ * 128;
    const int n0 = ntile_ * 128;
    const int shsrc = lane & 48;

    if (tid < 128) thrS[tid] = 0u;
    if (tid == 0) lcount = 0u;

    GEMM_CORE()
    __syncthreads();   // all waves done with GEMM; publish thrS/lcount init before epilogue

    float red[4][4];
    #pragma unroll
    for (int mt = 0; mt < 4; ++mt)
        #pragma unroll
        for (int r = 0; r < 4; ++r)
            red[mt][r] = fmaxf(fmaxf(acc[mt][0][r], acc[mt][1][r]),
                               fmaxf(acc[mt][2][r], acc[mt][3][r]));
    #pragma unroll
    for (int off = 1; off < 16; off <<= 1)
        #pragma unroll
        for (int mt = 0; mt < 4; ++mt)
            #pragma unroll
            for (int r = 0; r < 4; ++r)
                red[mt][r] = fmaxf(red[mt][r], __shfl_xor(red[mt][r], off));
    #pragma unroll
    for (int mt = 0; mt < 4; ++mt)
        #pragma unroll
        for (int r = 0; r < 4; ++r) {
            const int pl = wm * 64 + mt * 16 + quad * 4 + r;
            unsigned cur = 0;
            if (col == 0) {
                const unsigned enc = f2s(red[mt][r]);
                const unsigned old = atomicMax(&thrS[pl], enc);
                cur = old > enc ? old : enc;
            }
            cur = (unsigned)__shfl((int)cur, shsrc);
            red[mt][r] = s2f(cur) - DELTA;
        }

    const int ncode0 = n0 + wn * 64 + col;
    #pragma unroll
    for (int mt = 0; mt < 4; ++mt) {
        #pragma unroll
        for (int r = 0; r < 4; ++r) {
            const float tp = red[mt][r];
            const unsigned pt = m0 + wm * 64 + mt * 16 + quad * 4 + r;
            #pragma unroll
            for (int nt = 0; nt < 4; ++nt) {
                const float v = acc[mt][nt][r];
                if (v >= tp) {
                    const unsigned slot = atomicAdd(&lcount, 1u);
                    const u64 e = ((u64)((pt << 14) | (unsigned)(ncode0 + nt * 16)) << 32)
                                  | f2s(v);
                    if (slot < LCAP) lbuf[slot] = e;
                    else {
                        const unsigned g = atomicAdd(cnt, 1u);
                        if (g < cap) cand[g] = e;
                    }
                }
            }
        }
    }

    __syncthreads();
    if (tid < 128) atomicMax(&gmax[m0 + tid], thrS[tid]);
    const unsigned m_ = lcount < LCAP ? lcount : LCAP;
    if (tid == 0) lbase = atomicAdd(cnt, m_);
    __syncthreads();
    for (unsigned i = tid; i < m_; i += 256) {
        const unsigned g = lbase + i;
        if (g < cap) cand[g] = lbuf[i];
    }
}

// ---- phase 2: slices [16,128). Static thresholds from gmax. ----
__global__ __launch_bounds__(256, 3) void score_main(const unsigned short* __restrict__ zfbT,
                                                     const unsigned short* __restrict__ ewbT,
                                                     const unsigned* __restrict__ gmax,
                                                     u64* __restrict__ cand,
                                                     unsigned* __restrict__ cnt,
                                                     unsigned cap) {
    __shared__ float thrL[128];
    __shared__ u64 lbuf[LCAP];
    __shared__ unsigned lcount, lbase;

    const int tid = threadIdx.x, lane = tid & 63, wave = tid >> 6;
    const int quad = lane >> 4, col = lane & 15;
    const int wm = wave >> 1, wn = wave & 1;
    XCD_REMAP()
    const int m0 = mtile_ * 128;
    const int n0 = (16 + ntile_) * 128;

    if (tid < 128) thrL[tid] = s2f(gmax[m0 + tid]) - DELTA;
    if (tid == 0) lcount = 0u;

    GEMM_CORE()
    __syncthreads();   // all waves done with GEMM; publish thrL/lcount init before epilogue

    const int ncode0 = n0 + wn * 64 + col;
    #pragma unroll
    for (int mt = 0; mt < 4; ++mt) {
        #pragma unroll
        for (int r = 0; r < 4; ++r) {
            const int pl = wm * 64 + mt * 16 + quad * 4 + r;
            const float tp = thrL[pl];
            #pragma unroll
            for (int nt = 0; nt < 4; ++nt) {
                const float v = acc[mt][nt][r];
                if (v >= tp) {
                    const unsigned slot = atomicAdd(&lcount, 1u);
                    const u64 e = ((u64)(((unsigned)pl + m0) << 14 | (unsigned)(ncode0 + nt * 16)) << 32)
                                  | f2s(v);
                    if (slot < LCAP) lbuf[slot] = e;
                    else {
                        const unsigned g = atomicAdd(cnt, 1u);
                        if (g < cap) cand[g] = e;
                    }
                }
            }
        }
    }

    __syncthreads();
    const unsigned m_ = lcount < LCAP ? lcount : LCAP;
    if (tid == 0) lbase = atomicAdd(cnt, m_);
    __syncthreads();
    for (unsigned i = tid; i < m_; i += 256) {
        const unsigned g = lbase + i;
        if (g < cap) cand[g] = lbuf[i];
    }
}

// ---- final per-point bf16 max over candidates ----
__global__ __launch_bounds__(256) void cand_max(const u64* __restrict__ cand,
                                                const unsigned* __restrict__ cnt,
                                                unsigned* __restrict__ gmax,
                                                unsigned cap) {
    const unsigned total = min(cnt[0], cap);
    const unsigned stride = gridDim.x * 256;
    for (unsigned i = blockIdx.x * 256 + threadIdx.x; i < total; i += stride) {
        const u64 e = cand[i];
        atomicMax(&gmax[(unsigned)(e >> 46)], (unsigned)(e & 0xffffffffull));
    }
}

// ---- lane-parallel filter + ballot-compacted wave-cooperative fp32 rescore ----
__global__ __launch_bounds__(256) void rescore(const float* __restrict__ zf32,
                                               const float* __restrict__ E,
                                               const float* __restrict__ den,
                                               const unsigned* __restrict__ gmax,
                                               const u64* __restrict__ cand,
                                               const unsigned* __restrict__ cnt,
                                               u64* __restrict__ keys,
                                               unsigned cap) {
    const unsigned total = min(cnt[0], cap);
    const int lane = threadIdx.x & 63;
    const unsigned w = (blockIdx.x * 256 + threadIdx.x) >> 6;
    const unsigned nw = gridDim.x * 4;
    for (unsigned base = w * 64; base < total; base += nw * 64) {
        const unsigned i = base + lane;
        u64 e = 0;
        bool keep = false;
        if (i < total) {
            e = cand[i];
            const int p = (int)(e >> 46);
            keep = (s2f((unsigned)(e & 0xffffffffull)) >= s2f(gmax[p]) - DELTA);
        }
        u64 mask = __ballot(keep);
        while (mask) {
            const int src = __ffsll((long long)mask) - 1;
            mask &= mask - 1;
            const unsigned pc = (unsigned)__shfl((int)(unsigned)(e >> 32), src);
            const int p = pc >> 14, c = pc & 16383;
            const float dinv = 1.0f / den[c];
            const float4 a = *(const float4*)(zf32 + (size_t)p * D + lane * 4);
            const float4 b = *(const float4*)(E + (size_t)c * D + lane * 4);
            float sv = fmaf(a.x, b.x * dinv, fmaf(a.y, b.y * dinv,
                       fmaf(a.z, b.z * dinv, a.w * (b.w * dinv))));
            #pragma unroll
            for (int o = 1; o < 64; o <<= 1) sv += __shfl_xor(sv, o);
            if (lane == 0)
                atomicMax(keys + p, ((u64)f2s(sv) << 32) | (unsigned)(16383 - c));
        }
    }
}

// ---- gather + outputs (LDS transpose for coalesced zq writes) ----
__global__ __launch_bounds__(256) void finalize(const float* __restrict__ E,
                                                const float* __restrict__ den,
                                                const u64* __restrict__ keys,
                                                float* __restrict__ out) {
    __shared__ float t[32][257];
    __shared__ int sIdx[32];
    __shared__ float sDen[32];
    const int tid = threadIdx.x;
    const int n0 = blockIdx.x * 32;
    if (tid < 32) {
        const u64 key = keys[n0 + tid];
        const int idx = 16383 - (int)(unsigned)(key & 0xffffffffull);
        sIdx[tid] = idx;
        sDen[tid] = den[idx];
        out[O_IDX + n0 + tid] = (float)idx;
    }
    __syncthreads();
    const float S = 5.65685424949238019520675489683895f;  // sqrt(32)
    #pragma unroll 4
    for (int i = 0; i < 32; ++i) {
        const float v = E[(size_t)sIdx[i] * D + tid] / sDen[i];
        t[i][tid] = v;
        out[O_BIT + (size_t)(n0 + i) * D + tid] = (float)((int)(v * S) + 4);
    }
    __syncthreads();
    const int b = n0 >> 10, hw0 = n0 & 1023;
    const int hwl = tid & 31, cg = tid >> 5;
    #pragma unroll 4
    for (int cc = 0; cc < 32; ++cc) {
        const int c = cc * 8 + cg;
        out[(size_t)(b * 256 + c) * 1024 + hw0 + hwl] = t[hwl][c];
    }
    if (n0 == 0 && tid == 0) out[O_LOSS] = 0.0f;
}

extern "C" void kernel_launch(void* const* d_in, const int* in_sizes, int n_in,
                              void* d_out, int out_size, void* d_ws, size_t ws_size,
                              hipStream_t stream) {
    const float* z = (const float*)d_in[0];
    const float* E = (const float*)d_in[1];
    float* out = (float*)d_out;

    char* w = (char*)d_ws;
    unsigned short* ewbT = (unsigned short*)w;  w += (size_t)K * D * 2;      //  8 MB
    unsigned short* zfbT = (unsigned short*)w;  w += (size_t)NPTS * D * 2;   //  4 MB
    float*          zf32 = (float*)w;           w += (size_t)NPTS * D * 4;   //  8 MB
    u64*            keys = (u64*)w;             w += (size_t)NPTS * 8;       // 64 KB
    float*          den  = (float*)w;           w += (size_t)K * 4;          // 64 KB
    unsigned*       gmax = (unsigned*)w;        w += (size_t)NPTS * 4;       // 32 KB
    unsigned*       cnt  = (unsigned*)w;        w += 256;
    u64*            cand = (u64*)w;             // remainder of ws
    const size_t fixed = (size_t)(w - (char*)d_ws);
    const size_t avail = ws_size > fixed ? (ws_size - fixed) / 8 : 0;
    const unsigned cap = (unsigned)(avail < (size_t)MAXCAP ? avail : (size_t)MAXCAP);

    prep<<<640, 256, 0, stream>>>(E, z, den, ewbT, zfbT, zf32, gmax, keys, cnt);

    dim3 gpre(NPTS / 128, 16);
    score_seed<<<gpre, 256, 0, stream>>>(zfbT, ewbT, gmax, cand, cnt, cap);
    dim3 gmain(NPTS / 128, 112);
    score_main<<<gmain, 256, 0, stream>>>(zfbT, ewbT, gmax, cand, cnt, cap);

    cand_max<<<256, 256, 0, stream>>>(cand, cnt, gmax, cap);
    rescore<<<1024, 256, 0, stream>>>(zf32, E, den, gmax, cand, cnt, keys, cap);
    finalize<<<NPTS / 32, 256, 0, stream>>>(E, den, keys, out);
}

// Round 4
// 247.608 us; speedup vs baseline: 2.3769x; 2.3769x over previous
//
#include <hip/hip_runtime.h>
#include <math.h>

#define D      256
#define K      16384
#define NPTS   8192
#define DELTA  0.2f
#define LCAP   1024
#define MAXCAP 4000000u

// d_out layout (all f32): zq[8,256,32,32] | indices[8192] | bit[8,32,32,256] | loss[1]
#define O_IDX  2097152
#define O_BIT  2105344
#define O_LOSS 4202496

typedef __attribute__((ext_vector_type(8))) short bf16x8;
typedef __attribute__((ext_vector_type(4))) float f32x4;
typedef unsigned long long u64;

__device__ __forceinline__ unsigned f2s(float f) {
    unsigned u = __float_as_uint(f);
    return (u & 0x80000000u) ? ~u : (u | 0x80000000u);
}
__device__ __forceinline__ float s2f(unsigned s) {
    return __uint_as_float((s & 0x80000000u) ? (s & 0x7fffffffu) : ~s);
}
__device__ __forceinline__ unsigned short f2bf(float f) {  // RNE
    unsigned u = __float_as_uint(f);
    u += 0x7fffu + ((u >> 16) & 1u);
    return (unsigned short)(u >> 16);
}

// async global->LDS, 16B per lane (wave-uniform base + lane*16 dest)
__device__ __forceinline__ void gload16(const unsigned short* g, unsigned short* l) {
    __builtin_amdgcn_global_load_lds(
        (const __attribute__((address_space(1))) unsigned int*)g,
        (__attribute__((address_space(3))) unsigned int*)l, 16, 0, 0);
}

// generic LDS pointer -> 32-bit LDS byte offset for inline-asm ds_read
__device__ __forceinline__ unsigned lds_off(const void* p) {
    return (unsigned)(size_t)(const __attribute__((address_space(3))) void*)p;
}

// k-major fragment layouts: X[(k>>3)][row][8] bf16, 16B per (row, k-chunk)
//   zfbT: [32][NPTS][8] bf16 ; ewbT: [32][K][8] bf16

// ---- merged prep: blocks [0,512) codebook; [512,640) z transpose; state init folded ----
__global__ __launch_bounds__(256) void prep(const float* __restrict__ E,
                                            const float* __restrict__ z,
                                            float* __restrict__ den,
                                            unsigned short* __restrict__ ewbT,
                                            unsigned short* __restrict__ zfbT,
                                            float* __restrict__ zf32,
                                            unsigned* __restrict__ gmax,
                                            u64* __restrict__ keys,
                                            unsigned* __restrict__ cnt) {
    const int blk = blockIdx.x, tid = threadIdx.x;
    if (blk < 512) {
        const int lane = tid & 63, wave = tid >> 6;
        if (blk < 32)        gmax[blk * 256 + tid] = 0u;
        else if (blk < 64)   keys[(blk - 32) * 256 + tid] = 0ull;
        else if (blk == 64 && tid < 2) cnt[tid] = 0u;
        #pragma unroll
        for (int j = 0; j < 8; ++j) {
            const int row = blk * 32 + wave * 8 + j;
            const float4 v = *(const float4*)(E + (size_t)row * D + lane * 4);
            float ss = v.x * v.x + v.y * v.y + v.z * v.z + v.w * v.w;
            #pragma unroll
            for (int o = 1; o < 64; o <<= 1) ss += __shfl_xor(ss, o);
            const float dn = fmaxf(sqrtf(ss), 1e-12f);
            const unsigned lo = (unsigned)f2bf(v.x / dn) | ((unsigned)f2bf(v.y / dn) << 16);
            const unsigned hi = (unsigned)f2bf(v.z / dn) | ((unsigned)f2bf(v.w / dn) << 16);
            // k = lane*4 .. +4 -> chunk lane>>1, offset (lane&1)*4
            *(uint2*)(ewbT + ((size_t)(lane >> 1) * K + row) * 8 + (lane & 1) * 4)
                = make_uint2(lo, hi);
            if (lane == 0) den[row] = dn;
        }
    } else {
        const int bi = blk - 512;
        const int b = bi >> 4, hw0 = (bi & 15) * 64;
        __shared__ float t[64][65];
        for (int dc = 0; dc < D; dc += 64) {
            #pragma unroll
            for (int it = 0; it < 16; ++it) {
                const int idx = it * 256 + tid;
                const int dl = idx >> 6, hw = idx & 63;
                t[dl][hw] = z[(size_t)(b * 256 + dc + dl) * 1024 + hw0 + hw];
            }
            __syncthreads();
            #pragma unroll
            for (int it = 0; it < 16; ++it) {
                const int idx = it * 256 + tid;
                const int pl = idx >> 6, dl = idx & 63;
                const float v = t[dl][pl];
                const int p = b * 1024 + hw0 + pl, k = dc + dl;
                zfbT[((size_t)(k >> 3) * NPTS + p) * 8 + (k & 7)] = f2bf(v);
                zf32[(size_t)p * D + k] = v;
            }
            __syncthreads();
        }
    }
}

// ================= pipelined GEMM core =================
// 4 waves, 2x2 wave grid, tile 128m x 128n, BK=32, 8 K-steps, 3 LDS buffers, depth-2 prefetch.
// Per step: s_waitcnt vmcnt(4) [own tile-t loads landed; FIFO retirement] -> s_barrier
// [all waves' parts landed] -> STAGE(t+2) [overwrites buffer consumed at t-1; safe: each
// wave's t-1 ds_reads completed via its lgkmcnt(0) before it reached this barrier]
// -> COMPUTE(t). Only the final step drains vmcnt(0).
// KEY (round-4 fix): COMPUTE's fragment reads are inline-asm ds_read_b128. C-level LDS
// dereferences made the compiler insert its own s_waitcnt vmcnt(0) before them (it must
// assume the LDS-DMA writes alias), which drained the whole pipeline every K-step and made
// rounds 0-2 identical exposed-latency loops. With asm reads + explicit lgkmcnt(0) +
// sched_barrier(0) (rule #18), the counted vmcnt(4) schedule is actually preserved.
// LDS cell order permuted on the GLOBAL side (source row pp ^ (q<<1)) so fragment
// ds_read_b128s land 2-way per bank-group (free); reads undo the XOR.

#define STAGE(buf, t)                                                               \
    do {                                                                            \
        const size_t oA_ = (size_t)(t) * (4 * NPTS * 8);                            \
        const size_t oB_ = (size_t)(t) * (4 * K * 8);                               \
        gload16(gA0_ + oA_, &sA[buf][tid * 8]);                                     \
        gload16(gA1_ + oA_, &sA[buf][2048 + tid * 8]);                              \
        gload16(gB0_ + oB_, &sB[buf][tid * 8]);                                     \
        gload16(gB1_ + oB_, &sB[buf][2048 + tid * 8]);                              \
    } while (0)

#define COMPUTE(buf)                                                                \
    do {                                                                            \
        bf16x8 af_[4], bf_[4];                                                      \
        const unsigned aA_ = lds_off(&sA[buf][(size_t)sbA_ * 8]);                   \
        const unsigned aB_ = lds_off(&sB[buf][(size_t)sbB_ * 8]);                   \
        asm volatile("ds_read_b128 %0, %1"            : "=v"(af_[0]) : "v"(aA_));   \
        asm volatile("ds_read_b128 %0, %1 offset:256" : "=v"(af_[1]) : "v"(aA_));   \
        asm volatile("ds_read_b128 %0, %1 offset:512" : "=v"(af_[2]) : "v"(aA_));   \
        asm volatile("ds_read_b128 %0, %1 offset:768" : "=v"(af_[3]) : "v"(aA_));   \
        asm volatile("ds_read_b128 %0, %1"            : "=v"(bf_[0]) : "v"(aB_));   \
        asm volatile("ds_read_b128 %0, %1 offset:256" : "=v"(bf_[1]) : "v"(aB_));   \
        asm volatile("ds_read_b128 %0, %1 offset:512" : "=v"(bf_[2]) : "v"(aB_));   \
        asm volatile("ds_read_b128 %0, %1 offset:768" : "=v"(bf_[3]) : "v"(aB_));   \
        asm volatile("s_waitcnt lgkmcnt(0)" ::: "memory");                          \
        __builtin_amdgcn_sched_barrier(0);                                          \
        __builtin_amdgcn_s_setprio(1);                                              \
        _Pragma("unroll")                                                           \
        for (int mt = 0; mt < 4; ++mt)                                              \
            _Pragma("unroll")                                                       \
            for (int nt = 0; nt < 4; ++nt)                                          \
                acc[mt][nt] = __builtin_amdgcn_mfma_f32_16x16x32_bf16(af_[mt], bf_[nt], \
                                                                      acc[mt][nt], 0, 0, 0); \
        __builtin_amdgcn_s_setprio(0);                                              \
    } while (0)

// wait for own loads down to VM outstanding, then execution-barrier
#define WAITBAR(VM)                                                                 \
    asm volatile("s_waitcnt vmcnt(" VM ")" ::: "memory");                           \
    __builtin_amdgcn_s_barrier();                                                   \
    asm volatile("" ::: "memory");

#define GEMM_CORE()                                                                 \
    __shared__ unsigned short sA[3][4096];                                          \
    __shared__ unsigned short sB[3][4096];                                          \
    f32x4 acc[4][4];                                                                \
    _Pragma("unroll")                                                               \
    for (int i_ = 0; i_ < 4; ++i_)                                                  \
        _Pragma("unroll")                                                           \
        for (int j_ = 0; j_ < 4; ++j_) acc[i_][j_] = (f32x4){0.f, 0.f, 0.f, 0.f};   \
    const int q0_ = tid >> 7, q1_ = q0_ + 2, pp_ = tid & 127;                       \
    const unsigned short* gA0_ = zfbT + ((size_t)q0_ * NPTS + m0 + (pp_ ^ (q0_ << 1))) * 8; \
    const unsigned short* gA1_ = zfbT + ((size_t)q1_ * NPTS + m0 + (pp_ ^ (q1_ << 1))) * 8; \
    const unsigned short* gB0_ = ewbT + ((size_t)q0_ * K + n0 + (pp_ ^ (q0_ << 1))) * 8; \
    const unsigned short* gB1_ = ewbT + ((size_t)q1_ * K + n0 + (pp_ ^ (q1_ << 1))) * 8; \
    const int sbA_ = quad * 128 + ((wm * 64 + col) ^ (quad << 1));                  \
    const int sbB_ = quad * 128 + ((wn * 64 + col) ^ (quad << 1));                  \
    STAGE(0, 0);                                                                    \
    STAGE(1, 1);                                                                    \
    WAITBAR("4") STAGE(2, 2); COMPUTE(0);                                           \
    WAITBAR("4") STAGE(0, 3); COMPUTE(1);                                           \
    WAITBAR("4") STAGE(1, 4); COMPUTE(2);                                           \
    WAITBAR("4") STAGE(2, 5); COMPUTE(0);     /* buf 3%3=0 */                       \
    WAITBAR("4") STAGE(0, 6); COMPUTE(1);     /* buf 4%3=1 */                       \
    WAITBAR("4") STAGE(1, 7); COMPUTE(2);     /* buf 5%3=2 */                       \
    WAITBAR("4")              COMPUTE(0);     /* buf 6%3=0 */                       \
    WAITBAR("0")              COMPUTE(1);     /* buf 7%3=1 */

// XCD-chunked bijective decode from a 1-D grid (xcd = bid & 7 is the measured round-robin
// assignment for 1-D dispatch). XCD k owns m-tiles [8k, 8k+8): per-XCD zfbT footprint
// 512 KB (L2-resident for the whole kernel); n-slices walked slowly so one 64 KB ewbT
// slice at a time is L2-shared by the ~8 co-resident m-blocks on that XCD.
#define XCD_DECODE()                                                                \
    const unsigned bid_ = blockIdx.x;                                               \
    const unsigned j_ = bid_ >> 3;                                                  \
    const int mtile_ = (int)(((bid_ & 7u) << 3) | (j_ & 7u));                       \
    const int ntile_ = (int)(j_ >> 3);

// ---- phase 1: slices [0,16). Self-seeded thresholds; publishes block max at exit. ----
__global__ __launch_bounds__(256, 2) void score_seed(const unsigned short* __restrict__ zfbT,
                                                     const unsigned short* __restrict__ ewbT,
                                                     unsigned* __restrict__ gmax,
                                                     u64* __restrict__ cand,
                                                     unsigned* __restrict__ cnt,
                                                     unsigned cap) {
    __shared__ unsigned thrS[128];
    __shared__ u64 lbuf[LCAP];
    __shared__ unsigned lcount, lbase;

    const int tid = threadIdx.x, lane = tid & 63, wave = tid >> 6;
    const int quad = lane >> 4, col = lane & 15;
    const int wm = wave >> 1, wn = wave & 1;
    XCD_DECODE()
    const int m0 = mtile_ * 128;
    const int n0 = ntile_ * 128;
    const int shsrc = lane & 48;

    if (tid < 128) thrS[tid] = 0u;
    if (tid == 0) lcount = 0u;

    GEMM_CORE()
    __syncthreads();   // all waves done with GEMM; publish thrS/lcount init before epilogue

    float red[4][4];
    #pragma unroll
    for (int mt = 0; mt < 4; ++mt)
        #pragma unroll
        for (int r = 0; r < 4; ++r)
            red[mt][r] = fmaxf(fmaxf(acc[mt][0][r], acc[mt][1][r]),
                               fmaxf(acc[mt][2][r], acc[mt][3][r]));
    #pragma unroll
    for (int off = 1; off < 16; off <<= 1)
        #pragma unroll
        for (int mt = 0; mt < 4; ++mt)
            #pragma unroll
            for (int r = 0; r < 4; ++r)
                red[mt][r] = fmaxf(red[mt][r], __shfl_xor(red[mt][r], off));
    #pragma unroll
    for (int mt = 0; mt < 4; ++mt)
        #pragma unroll
        for (int r = 0; r < 4; ++r) {
            const int pl = wm * 64 + mt * 16 + quad * 4 + r;
            unsigned cur = 0;
            if (col == 0) {
                const unsigned enc = f2s(red[mt][r]);
                const unsigned old = atomicMax(&thrS[pl], enc);
                cur = old > enc ? old : enc;
            }
            cur = (unsigned)__shfl((int)cur, shsrc);
            red[mt][r] = s2f(cur) - DELTA;
        }

    const int ncode0 = n0 + wn * 64 + col;
    #pragma unroll
    for (int mt = 0; mt < 4; ++mt) {
        #pragma unroll
        for (int r = 0; r < 4; ++r) {
            const float tp = red[mt][r];
            const unsigned pt = m0 + wm * 64 + mt * 16 + quad * 4 + r;
            #pragma unroll
            for (int nt = 0; nt < 4; ++nt) {
                const float v = acc[mt][nt][r];
                if (v >= tp) {
                    const unsigned slot = atomicAdd(&lcount, 1u);
                    const u64 e = ((u64)((pt << 14) | (unsigned)(ncode0 + nt * 16)) << 32)
                                  | f2s(v);
                    if (slot < LCAP) lbuf[slot] = e;
                    else {
                        const unsigned g = atomicAdd(cnt, 1u);
                        if (g < cap) cand[g] = e;
                    }
                }
            }
        }
    }

    __syncthreads();
    if (tid < 128) atomicMax(&gmax[m0 + tid], thrS[tid]);
    const unsigned m_ = lcount < LCAP ? lcount : LCAP;
    if (tid == 0) lbase = atomicAdd(cnt, m_);
    __syncthreads();
    for (unsigned i = tid; i < m_; i += 256) {
        const unsigned g = lbase + i;
        if (g < cap) cand[g] = lbuf[i];
    }
}

// ---- phase 2: slices [16,128). Static thresholds from gmax. ----
__global__ __launch_bounds__(256, 2) void score_main(const unsigned short* __restrict__ zfbT,
                                                     const unsigned short* __restrict__ ewbT,
                                                     const unsigned* __restrict__ gmax,
                                                     u64* __restrict__ cand,
                                                     unsigned* __restrict__ cnt,
                                                     unsigned cap) {
    __shared__ float thrL[128];
    __shared__ u64 lbuf[LCAP];
    __shared__ unsigned lcount, lbase;

    const int tid = threadIdx.x, lane = tid & 63, wave = tid >> 6;
    const int quad = lane >> 4, col = lane & 15;
    const int wm = wave >> 1, wn = wave & 1;
    XCD_DECODE()
    const int m0 = mtile_ * 128;
    const int n0 = (16 + ntile_) * 128;

    if (tid < 128) thrL[tid] = s2f(gmax[m0 + tid]) - DELTA;
    if (tid == 0) lcount = 0u;

    GEMM_CORE()
    __syncthreads();   // all waves done with GEMM; publish thrL/lcount init before epilogue

    const int ncode0 = n0 + wn * 64 + col;
    #pragma unroll
    for (int mt = 0; mt < 4; ++mt) {
        #pragma unroll
        for (int r = 0; r < 4; ++r) {
            const int pl = wm * 64 + mt * 16 + quad * 4 + r;
            const float tp = thrL[pl];
            #pragma unroll
            for (int nt = 0; nt < 4; ++nt) {
                const float v = acc[mt][nt][r];
                if (v >= tp) {
                    const unsigned slot = atomicAdd(&lcount, 1u);
                    const u64 e = ((u64)(((unsigned)pl + m0) << 14 | (unsigned)(ncode0 + nt * 16)) << 32)
                                  | f2s(v);
                    if (slot < LCAP) lbuf[slot] = e;
                    else {
                        const unsigned g = atomicAdd(cnt, 1u);
                        if (g < cap) cand[g] = e;
                    }
                }
            }
        }
    }

    __syncthreads();
    const unsigned m_ = lcount < LCAP ? lcount : LCAP;
    if (tid == 0) lbase = atomicAdd(cnt, m_);
    __syncthreads();
    for (unsigned i = tid; i < m_; i += 256) {
        const unsigned g = lbase + i;
        if (g < cap) cand[g] = lbuf[i];
    }
}

// ---- final per-point bf16 max over candidates ----
__global__ __launch_bounds__(256) void cand_max(const u64* __restrict__ cand,
                                                const unsigned* __restrict__ cnt,
                                                unsigned* __restrict__ gmax,
                                                unsigned cap) {
    const unsigned total = min(cnt[0], cap);
    const unsigned stride = gridDim.x * 256;
    for (unsigned i = blockIdx.x * 256 + threadIdx.x; i < total; i += stride) {
        const u64 e = cand[i];
        atomicMax(&gmax[(unsigned)(e >> 46)], (unsigned)(e & 0xffffffffull));
    }
}

// ---- lane-parallel filter + ballot-compacted wave-cooperative fp32 rescore ----
__global__ __launch_bounds__(256) void rescore(const float* __restrict__ zf32,
                                               const float* __restrict__ E,
                                               const float* __restrict__ den,
                                               const unsigned* __restrict__ gmax,
                                               const u64* __restrict__ cand,
                                               const unsigned* __restrict__ cnt,
                                               u64* __restrict__ keys,
                                               unsigned cap) {
    const unsigned total = min(cnt[0], cap);
    const int lane = threadIdx.x & 63;
    const unsigned w = (blockIdx.x * 256 + threadIdx.x) >> 6;
    const unsigned nw = gridDim.x * 4;
    for (unsigned base = w * 64; base < total; base += nw * 64) {
        const unsigned i = base + lane;
        u64 e = 0;
        bool keep = false;
        if (i < total) {
            e = cand[i];
            const int p = (int)(e >> 46);
            keep = (s2f((unsigned)(e & 0xffffffffull)) >= s2f(gmax[p]) - DELTA);
        }
        u64 mask = __ballot(keep);
        while (mask) {
            const int src = __ffsll((long long)mask) - 1;
            mask &= mask - 1;
            const unsigned pc = (unsigned)__shfl((int)(unsigned)(e >> 32), src);
            const int p = pc >> 14, c = pc & 16383;
            const float dinv = 1.0f / den[c];
            const float4 a = *(const float4*)(zf32 + (size_t)p * D + lane * 4);
            const float4 b = *(const float4*)(E + (size_t)c * D + lane * 4);
            float sv = fmaf(a.x, b.x * dinv, fmaf(a.y, b.y * dinv,
                       fmaf(a.z, b.z * dinv, a.w * (b.w * dinv))));
            #pragma unroll
            for (int o = 1; o < 64; o <<= 1) sv += __shfl_xor(sv, o);
            if (lane == 0)
                atomicMax(keys + p, ((u64)f2s(sv) << 32) | (unsigned)(16383 - c));
        }
    }
}

// ---- gather + outputs (LDS transpose for coalesced zq writes) ----
__global__ __launch_bounds__(256) void finalize(const float* __restrict__ E,
                                                const float* __restrict__ den,
                                                const u64* __restrict__ keys,
                                                float* __restrict__ out) {
    __shared__ float t[32][257];
    __shared__ int sIdx[32];
    __shared__ float sDen[32];
    const int tid = threadIdx.x;
    const int n0 = blockIdx.x * 32;
    if (tid < 32) {
        const u64 key = keys[n0 + tid];
        const int idx = 16383 - (int)(unsigned)(key & 0xffffffffull);
        sIdx[tid] = idx;
        sDen[tid] = den[idx];
        out[O_IDX + n0 + tid] = (float)idx;
    }
    __syncthreads();
    const float S = 5.65685424949238019520675489683895f;  // sqrt(32)
    #pragma unroll 4
    for (int i = 0; i < 32; ++i) {
        const float v = E[(size_t)sIdx[i] * D + tid] / sDen[i];
        t[i][tid] = v;
        out[O_BIT + (size_t)(n0 + i) * D + tid] = (float)((int)(v * S) + 4);
    }
    __syncthreads();
    const int b = n0 >> 10, hw0 = n0 & 1023;
    const int hwl = tid & 31, cg = tid >> 5;
    #pragma unroll 4
    for (int cc = 0; cc < 32; ++cc) {
        const int c = cc * 8 + cg;
        out[(size_t)(b * 256 + c) * 1024 + hw0 + hwl] = t[hwl][c];
    }
    if (n0 == 0 && tid == 0) out[O_LOSS] = 0.0f;
}

extern "C" void kernel_launch(void* const* d_in, const int* in_sizes, int n_in,
                              void* d_out, int out_size, void* d_ws, size_t ws_size,
                              hipStream_t stream) {
    const float* z = (const float*)d_in[0];
    const float* E = (const float*)d_in[1];
    float* out = (float*)d_out;

    char* w = (char*)d_ws;
    unsigned short* ewbT = (unsigned short*)w;  w += (size_t)K * D * 2;      //  8 MB
    unsigned short* zfbT = (unsigned short*)w;  w += (size_t)NPTS * D * 2;   //  4 MB
    float*          zf32 = (float*)w;           w += (size_t)NPTS * D * 4;   //  8 MB
    u64*            keys = (u64*)w;             w += (size_t)NPTS * 8;       // 64 KB
    float*          den  = (float*)w;           w += (size_t)K * 4;          // 64 KB
    unsigned*       gmax = (unsigned*)w;        w += (size_t)NPTS * 4;       // 32 KB
    unsigned*       cnt  = (unsigned*)w;        w += 256;
    u64*            cand = (u64*)w;             // remainder of ws
    const size_t fixed = (size_t)(w - (char*)d_ws);
    const size_t avail = ws_size > fixed ? (ws_size - fixed) / 8 : 0;
    const unsigned cap = (unsigned)(avail < (size_t)MAXCAP ? avail : (size_t)MAXCAP);

    prep<<<640, 256, 0, stream>>>(E, z, den, ewbT, zfbT, zf32, gmax, keys, cnt);

    score_seed<<<1024, 256, 0, stream>>>(zfbT, ewbT, gmax, cand, cnt, cap);
    score_main<<<7168, 256, 0, stream>>>(zfbT, ewbT, gmax, cand, cnt, cap);

    cand_max<<<256, 256, 0, stream>>>(cand, cnt, gmax, cap);
    rescore<<<1024, 256, 0, stream>>>(zf32, E, den, gmax, cand, cnt, keys, cap);
    finalize<<<NPTS / 32, 256, 0, stream>>>(E, den, keys, out);
}

// Round 5
// 234.501 us; speedup vs baseline: 2.5097x; 1.0559x over previous
//
#include <hip/hip_runtime.h>
#include <math.h>

#define D      256
#define K      16384
#define NPTS   8192
#define DELTA  0.2f
#define LCAP   2048
#define MAXCAP 4000000u

// d_out layout (all f32): zq[8,256,32,32] | indices[8192] | bit[8,32,32,256] | loss[1]
#define O_IDX  2097152
#define O_BIT  2105344
#define O_LOSS 4202496

typedef __attribute__((ext_vector_type(8))) short bf16x8;
typedef __attribute__((ext_vector_type(4))) float f32x4;
typedef unsigned long long u64;

__device__ __forceinline__ unsigned f2s(float f) {
    unsigned u = __float_as_uint(f);
    return (u & 0x80000000u) ? ~u : (u | 0x80000000u);
}
__device__ __forceinline__ float s2f(unsigned s) {
    return __uint_as_float((s & 0x80000000u) ? (s & 0x7fffffffu) : ~s);
}
__device__ __forceinline__ unsigned short f2bf(float f) {  // RNE
    unsigned u = __float_as_uint(f);
    u += 0x7fffu + ((u >> 16) & 1u);
    return (unsigned short)(u >> 16);
}

// async global->LDS, 16B per lane (wave-uniform base + lane*16 dest)
__device__ __forceinline__ void gload16(const unsigned short* g, unsigned short* l) {
    __builtin_amdgcn_global_load_lds(
        (const __attribute__((address_space(1))) unsigned int*)g,
        (__attribute__((address_space(3))) unsigned int*)l, 16, 0, 0);
}

// generic LDS pointer -> 32-bit LDS byte offset for inline-asm ds_read
__device__ __forceinline__ unsigned lds_off(const void* p) {
    return (unsigned)(size_t)(const __attribute__((address_space(3))) void*)p;
}

// k-major fragment layouts: X[(k>>3)][row][8] bf16, 16B per (row, k-chunk)
//   zfbT: [32][NPTS][8] bf16 ; ewbT: [32][K][8] bf16

// ---- merged prep: blocks [0,512) codebook; [512,640) z transpose; state init folded ----
__global__ __launch_bounds__(256) void prep(const float* __restrict__ E,
                                            const float* __restrict__ z,
                                            float* __restrict__ den,
                                            unsigned short* __restrict__ ewbT,
                                            unsigned short* __restrict__ zfbT,
                                            float* __restrict__ zf32,
                                            unsigned* __restrict__ gmax,
                                            u64* __restrict__ keys,
                                            unsigned* __restrict__ cnt) {
    const int blk = blockIdx.x, tid = threadIdx.x;
    if (blk < 512) {
        const int lane = tid & 63, wave = tid >> 6;
        if (blk < 32)        gmax[blk * 256 + tid] = 0u;
        else if (blk < 64)   keys[(blk - 32) * 256 + tid] = 0ull;
        else if (blk == 64 && tid < 2) cnt[tid] = 0u;
        #pragma unroll
        for (int j = 0; j < 8; ++j) {
            const int row = blk * 32 + wave * 8 + j;
            const float4 v = *(const float4*)(E + (size_t)row * D + lane * 4);
            float ss = v.x * v.x + v.y * v.y + v.z * v.z + v.w * v.w;
            #pragma unroll
            for (int o = 1; o < 64; o <<= 1) ss += __shfl_xor(ss, o);
            const float dn = fmaxf(sqrtf(ss), 1e-12f);
            const unsigned lo = (unsigned)f2bf(v.x / dn) | ((unsigned)f2bf(v.y / dn) << 16);
            const unsigned hi = (unsigned)f2bf(v.z / dn) | ((unsigned)f2bf(v.w / dn) << 16);
            // k = lane*4 .. +4 -> chunk lane>>1, offset (lane&1)*4
            *(uint2*)(ewbT + ((size_t)(lane >> 1) * K + row) * 8 + (lane & 1) * 4)
                = make_uint2(lo, hi);
            if (lane == 0) den[row] = dn;
        }
    } else {
        const int bi = blk - 512;
        const int b = bi >> 4, hw0 = (bi & 15) * 64;
        __shared__ float t[64][65];
        for (int dc = 0; dc < D; dc += 64) {
            #pragma unroll
            for (int it = 0; it < 16; ++it) {
                const int idx = it * 256 + tid;
                const int dl = idx >> 6, hw = idx & 63;
                t[dl][hw] = z[(size_t)(b * 256 + dc + dl) * 1024 + hw0 + hw];
            }
            __syncthreads();
            #pragma unroll
            for (int it = 0; it < 16; ++it) {
                const int idx = it * 256 + tid;
                const int pl = idx >> 6, dl = idx & 63;
                const float v = t[dl][pl];
                const int p = b * 1024 + hw0 + pl, k = dc + dl;
                zfbT[((size_t)(k >> 3) * NPTS + p) * 8 + (k & 7)] = f2bf(v);
                zf32[(size_t)p * D + k] = v;
            }
            __syncthreads();
        }
    }
}

// ================= 256x256-tile pipelined GEMM core =================
// 512 threads = 8 waves (2m x 4n), per-wave output 128x64 (acc[8][4]), BK=64 (8 k-chunks),
// 4 K-tiles, 2 LDS buffers (A 32KB + B 32KB each; 128KB total), depth-2 counted-vmcnt
// pipeline. Per K-tile: vmcnt(8)+barrier [tile t landed] -> kk0 {12 asm ds_read, lgkm(0),
// sched_barrier, 32 MFMA} -> kk1 reads + lgkm(0) -> barrier [all waves done reading buf]
// -> STAGE(buf, t+2) [8 gloads] -> kk1 32 MFMA. Only the last tile drains vmcnt(0).
// Ledger: buf(t) written by STAGE issued at t-2 mid; read at t after vmcnt(8) retires the
// oldest 8 loads (FIFO, m135) + barrier (all waves landed). Overwrite at t mid is preceded
// by a barrier each wave reaches only after its lgkmcnt(0) completed all reads of buf.
// LDS cell order permuted on the GLOBAL side (source row r ^ (chunk<<1)) so fragment
// ds_read_b128s keep the measured-zero bank-conflict pattern; reads undo the XOR.

#define STAGE(buf, t)                                                               \
    do {                                                                            \
        const size_t oA_ = (size_t)(t) * (8u * NPTS * 8);                           \
        const size_t oB_ = (size_t)(t) * (8u * K * 8);                              \
        unsigned short* dA_ = &sA[buf][0][0][0];                                    \
        unsigned short* dB_ = &sB[buf][0][0][0];                                    \
        gload16(gA0_ + oA_, dA_ + (size_t)tid * 8);                                 \
        gload16(gA1_ + oA_, dA_ + (size_t)(512 + tid) * 8);                         \
        gload16(gA2_ + oA_, dA_ + (size_t)(1024 + tid) * 8);                        \
        gload16(gA3_ + oA_, dA_ + (size_t)(1536 + tid) * 8);                        \
        gload16(gB0_ + oB_, dB_ + (size_t)tid * 8);                                 \
        gload16(gB1_ + oB_, dB_ + (size_t)(512 + tid) * 8);                         \
        gload16(gB2_ + oB_, dB_ + (size_t)(1024 + tid) * 8);                        \
        gload16(gB3_ + oB_, dB_ + (size_t)(1536 + tid) * 8);                        \
    } while (0)

#define RKK(buf, AA, BB)                                                            \
    do {                                                                            \
        const unsigned a__ = (AA) + (unsigned)((buf) * 32768);                      \
        const unsigned b__ = (BB) + (unsigned)((buf) * 32768);                      \
        asm volatile("ds_read_b128 %0, %1"             : "=v"(af_[0]) : "v"(a__));  \
        asm volatile("ds_read_b128 %0, %1 offset:256"  : "=v"(af_[1]) : "v"(a__));  \
        asm volatile("ds_read_b128 %0, %1 offset:512"  : "=v"(af_[2]) : "v"(a__));  \
        asm volatile("ds_read_b128 %0, %1 offset:768"  : "=v"(af_[3]) : "v"(a__));  \
        asm volatile("ds_read_b128 %0, %1 offset:1024" : "=v"(af_[4]) : "v"(a__));  \
        asm volatile("ds_read_b128 %0, %1 offset:1280" : "=v"(af_[5]) : "v"(a__));  \
        asm volatile("ds_read_b128 %0, %1 offset:1536" : "=v"(af_[6]) : "v"(a__));  \
        asm volatile("ds_read_b128 %0, %1 offset:1792" : "=v"(af_[7]) : "v"(a__));  \
        asm volatile("ds_read_b128 %0, %1"             : "=v"(bf_[0]) : "v"(b__));  \
        asm volatile("ds_read_b128 %0, %1 offset:256"  : "=v"(bf_[1]) : "v"(b__));  \
        asm volatile("ds_read_b128 %0, %1 offset:512"  : "=v"(bf_[2]) : "v"(b__));  \
        asm volatile("ds_read_b128 %0, %1 offset:768"  : "=v"(bf_[3]) : "v"(b__));  \
    } while (0)

#define LGKM_SB                                                                     \
    asm volatile("s_waitcnt lgkmcnt(0)" ::: "memory");                              \
    __builtin_amdgcn_sched_barrier(0);

#define MFMAS                                                                       \
    do {                                                                            \
        __builtin_amdgcn_s_setprio(1);                                              \
        _Pragma("unroll")                                                           \
        for (int mt = 0; mt < 8; ++mt)                                              \
            _Pragma("unroll")                                                       \
            for (int nt = 0; nt < 4; ++nt)                                          \
                acc[mt][nt] = __builtin_amdgcn_mfma_f32_16x16x32_bf16(af_[mt], bf_[nt], \
                                                                      acc[mt][nt], 0, 0, 0); \
        __builtin_amdgcn_s_setprio(0);                                              \
    } while (0)

#define WAITBAR(VM)                                                                 \
    asm volatile("s_waitcnt vmcnt(" VM ")" ::: "memory");                           \
    __builtin_amdgcn_s_barrier();                                                   \
    asm volatile("" ::: "memory");

#define BARFENCE                                                                    \
    __builtin_amdgcn_s_barrier();                                                   \
    asm volatile("" ::: "memory");

#define GEMM_CORE()                                                                 \
    __shared__ unsigned short sA[2][8][256][8];                                     \
    __shared__ unsigned short sB[2][8][256][8];                                     \
    f32x4 acc[8][4];                                                                \
    _Pragma("unroll")                                                               \
    for (int i_ = 0; i_ < 8; ++i_)                                                  \
        _Pragma("unroll")                                                           \
        for (int j_ = 0; j_ < 4; ++j_) acc[i_][j_] = (f32x4){0.f, 0.f, 0.f, 0.f};   \
    bf16x8 af_[8], bf_[4];                                                          \
    const int th_ = tid & 255, hi_ = tid >> 8;                                      \
    const int c0_ = hi_, c1_ = 2 + hi_, c2_ = 4 + hi_, c3_ = 6 + hi_;               \
    const unsigned short* gA0_ = zfbT + ((size_t)c0_ * NPTS + m0 + (th_ ^ (c0_ << 1))) * 8; \
    const unsigned short* gA1_ = zfbT + ((size_t)c1_ * NPTS + m0 + (th_ ^ (c1_ << 1))) * 8; \
    const unsigned short* gA2_ = zfbT + ((size_t)c2_ * NPTS + m0 + (th_ ^ (c2_ << 1))) * 8; \
    const unsigned short* gA3_ = zfbT + ((size_t)c3_ * NPTS + m0 + (th_ ^ (c3_ << 1))) * 8; \
    const unsigned short* gB0_ = ewbT + ((size_t)c0_ * K + n0 + (th_ ^ (c0_ << 1))) * 8; \
    const unsigned short* gB1_ = ewbT + ((size_t)c1_ * K + n0 + (th_ ^ (c1_ << 1))) * 8; \
    const unsigned short* gB2_ = ewbT + ((size_t)c2_ * K + n0 + (th_ ^ (c2_ << 1))) * 8; \
    const unsigned short* gB3_ = ewbT + ((size_t)c3_ * K + n0 + (th_ ^ (c3_ << 1))) * 8; \
    const unsigned sAb_ = lds_off(&sA[0][0][0][0]);                                 \
    const unsigned sBb_ = lds_off(&sB[0][0][0][0]);                                 \
    const int ck0_ = quad, ck1_ = 4 + quad;                                         \
    const unsigned aA0_ = sAb_ + (unsigned)((ck0_ * 256 + ((wm * 128 + col) ^ (ck0_ << 1))) * 16); \
    const unsigned aA1_ = sAb_ + (unsigned)((ck1_ * 256 + ((wm * 128 + col) ^ (ck1_ << 1))) * 16); \
    const unsigned bB0_ = sBb_ + (unsigned)((ck0_ * 256 + ((wn * 64 + col) ^ (ck0_ << 1))) * 16); \
    const unsigned bB1_ = sBb_ + (unsigned)((ck1_ * 256 + ((wn * 64 + col) ^ (ck1_ << 1))) * 16); \
    STAGE(0, 0);                                                                    \
    STAGE(1, 1);                                                                    \
    WAITBAR("8")                                                                    \
    RKK(0, aA0_, bB0_); LGKM_SB; MFMAS;                                             \
    RKK(0, aA1_, bB1_); LGKM_SB; BARFENCE; STAGE(0, 2); MFMAS;                      \
    WAITBAR("8")                                                                    \
    RKK(1, aA0_, bB0_); LGKM_SB; MFMAS;                                             \
    RKK(1, aA1_, bB1_); LGKM_SB; BARFENCE; STAGE(1, 3); MFMAS;                      \
    WAITBAR("8")                                                                    \
    RKK(0, aA0_, bB0_); LGKM_SB; MFMAS;                                             \
    RKK(0, aA1_, bB1_); LGKM_SB; MFMAS;                                             \
    WAITBAR("0")                                                                    \
    RKK(1, aA0_, bB0_); LGKM_SB; MFMAS;                                             \
    RKK(1, aA1_, bB1_); LGKM_SB; MFMAS;

// wave-aggregated global overflow append: one atomic per wave per batch (round-3 lesson:
// per-candidate same-address atomics serialize catastrophically)
#define CAND_APPEND(e)                                                              \
    do {                                                                            \
        const u64 am_ = __builtin_amdgcn_read_exec();                               \
        const unsigned n_ = (unsigned)__popcll(am_);                                \
        const unsigned rk_ = (unsigned)__popcll(am_ & ((1ull << lane) - 1));        \
        unsigned base_ = 0;                                                         \
        if (rk_ == 0) base_ = atomicAdd(cnt, n_);                                   \
        base_ = (unsigned)__builtin_amdgcn_readfirstlane((int)base_);               \
        const unsigned g_ = base_ + rk_;                                            \
        if (g_ < cap) cand[g_] = (e);                                               \
    } while (0)

// XCD-chunked bijective decode (1-D grid, xcd = bid & 7). XCD k owns mtiles [4k, 4k+4):
// per-XCD A footprint 4 x 131KB = 524KB L2-resident; n-tiles walked slowly.
#define XCD_DECODE(NT0)                                                             \
    const unsigned bid_ = blockIdx.x;                                               \
    const unsigned j_ = bid_ >> 3;                                                  \
    const int m0 = (int)(((bid_ & 7u) << 2) | (j_ & 3u)) * 256;                     \
    const int n0 = (NT0) + (int)(j_ >> 2) * 256;

// ---- phase 1: codes [0,2048). Self-seeded thresholds; publishes block max at exit. ----
__global__ __launch_bounds__(512, 2) void score_seed(const unsigned short* __restrict__ zfbT,
                                                     const unsigned short* __restrict__ ewbT,
                                                     unsigned* __restrict__ gmax,
                                                     u64* __restrict__ cand,
                                                     unsigned* __restrict__ cnt,
                                                     unsigned cap) {
    __shared__ unsigned thrS[256];
    __shared__ u64 lbuf[LCAP];
    __shared__ unsigned lcount, lbase;

    const int tid = threadIdx.x, lane = tid & 63, wave = tid >> 6;
    const int quad = lane >> 4, col = lane & 15;
    const int wm = wave >> 2, wn = wave & 3;
    XCD_DECODE(0)
    const int shsrc = lane & 48;

    if (tid < 256) thrS[tid] = 0u;
    if (tid == 0) lcount = 0u;

    GEMM_CORE()
    __syncthreads();   // all waves done with GEMM; publish thrS/lcount init before epilogue

    float red[8][4];
    #pragma unroll
    for (int mt = 0; mt < 8; ++mt)
        #pragma unroll
        for (int r = 0; r < 4; ++r)
            red[mt][r] = fmaxf(fmaxf(acc[mt][0][r], acc[mt][1][r]),
                               fmaxf(acc[mt][2][r], acc[mt][3][r]));
    #pragma unroll
    for (int off = 1; off < 16; off <<= 1)
        #pragma unroll
        for (int mt = 0; mt < 8; ++mt)
            #pragma unroll
            for (int r = 0; r < 4; ++r)
                red[mt][r] = fmaxf(red[mt][r], __shfl_xor(red[mt][r], off));
    #pragma unroll
    for (int mt = 0; mt < 8; ++mt)
        #pragma unroll
        for (int r = 0; r < 4; ++r) {
            const int pl = wm * 128 + mt * 16 + quad * 4 + r;
            unsigned cur = 0;
            if (col == 0) {
                const unsigned enc = f2s(red[mt][r]);
                const unsigned old = atomicMax(&thrS[pl], enc);
                cur = old > enc ? old : enc;
            }
            cur = (unsigned)__shfl((int)cur, shsrc);
            red[mt][r] = s2f(cur) - DELTA;
        }

    const int ncode0 = n0 + wn * 64 + col;
    #pragma unroll
    for (int mt = 0; mt < 8; ++mt) {
        #pragma unroll
        for (int r = 0; r < 4; ++r) {
            const float tp = red[mt][r];
            const unsigned pt = m0 + wm * 128 + mt * 16 + quad * 4 + r;
            #pragma unroll
            for (int nt = 0; nt < 4; ++nt) {
                const float v = acc[mt][nt][r];
                if (v >= tp) {
                    const unsigned slot = atomicAdd(&lcount, 1u);
                    const u64 e = ((u64)((pt << 14) | (unsigned)(ncode0 + nt * 16)) << 32)
                                  | f2s(v);
                    if (slot < LCAP) lbuf[slot] = e;
                    else CAND_APPEND(e);
                }
            }
        }
    }

    __syncthreads();
    if (tid < 256) atomicMax(&gmax[m0 + tid], thrS[tid]);
    const unsigned m_ = lcount < LCAP ? lcount : LCAP;
    if (tid == 0) lbase = atomicAdd(cnt, m_);
    __syncthreads();
    for (unsigned i = tid; i < m_; i += 512) {
        const unsigned g = lbase + i;
        if (g < cap) cand[g] = lbuf[i];
    }
}

// ---- phase 2: codes [2048,16384). Static thresholds from gmax. ----
__global__ __launch_bounds__(512, 2) void score_main(const unsigned short* __restrict__ zfbT,
                                                     const unsigned short* __restrict__ ewbT,
                                                     const unsigned* __restrict__ gmax,
                                                     u64* __restrict__ cand,
                                                     unsigned* __restrict__ cnt,
                                                     unsigned cap) {
    __shared__ float thrL[256];
    __shared__ u64 lbuf[LCAP];
    __shared__ unsigned lcount, lbase;

    const int tid = threadIdx.x, lane = tid & 63, wave = tid >> 6;
    const int quad = lane >> 4, col = lane & 15;
    const int wm = wave >> 2, wn = wave & 3;
    XCD_DECODE(2048)

    if (tid < 256) thrL[tid] = s2f(gmax[m0 + tid]) - DELTA;
    if (tid == 0) lcount = 0u;

    GEMM_CORE()
    __syncthreads();   // all waves done with GEMM; publish thrL/lcount init before epilogue

    const int ncode0 = n0 + wn * 64 + col;
    #pragma unroll
    for (int mt = 0; mt < 8; ++mt) {
        #pragma unroll
        for (int r = 0; r < 4; ++r) {
            const int pl = wm * 128 + mt * 16 + quad * 4 + r;
            const float tp = thrL[pl];
            #pragma unroll
            for (int nt = 0; nt < 4; ++nt) {
                const float v = acc[mt][nt][r];
                if (v >= tp) {
                    const unsigned slot = atomicAdd(&lcount, 1u);
                    const u64 e = ((u64)(((unsigned)pl + m0) << 14 | (unsigned)(ncode0 + nt * 16)) << 32)
                                  | f2s(v);
                    if (slot < LCAP) lbuf[slot] = e;
                    else CAND_APPEND(e);
                }
            }
        }
    }

    __syncthreads();
    const unsigned m_ = lcount < LCAP ? lcount : LCAP;
    if (tid == 0) lbase = atomicAdd(cnt, m_);
    __syncthreads();
    for (unsigned i = tid; i < m_; i += 512) {
        const unsigned g = lbase + i;
        if (g < cap) cand[g] = lbuf[i];
    }
}

// ---- final per-point bf16 max over candidates ----
__global__ __launch_bounds__(256) void cand_max(const u64* __restrict__ cand,
                                                const unsigned* __restrict__ cnt,
                                                unsigned* __restrict__ gmax,
                                                unsigned cap) {
    const unsigned total = min(cnt[0], cap);
    const unsigned stride = gridDim.x * 256;
    for (unsigned i = blockIdx.x * 256 + threadIdx.x; i < total; i += stride) {
        const u64 e = cand[i];
        atomicMax(&gmax[(unsigned)(e >> 46)], (unsigned)(e & 0xffffffffull));
    }
}

// ---- lane-parallel filter + ballot-compacted wave-cooperative fp32 rescore ----
__global__ __launch_bounds__(256) void rescore(const float* __restrict__ zf32,
                                               const float* __restrict__ E,
                                               const float* __restrict__ den,
                                               const unsigned* __restrict__ gmax,
                                               const u64* __restrict__ cand,
                                               const unsigned* __restrict__ cnt,
                                               u64* __restrict__ keys,
                                               unsigned cap) {
    const unsigned total = min(cnt[0], cap);
    const int lane = threadIdx.x & 63;
    const unsigned w = (blockIdx.x * 256 + threadIdx.x) >> 6;
    const unsigned nw = gridDim.x * 4;
    for (unsigned base = w * 64; base < total; base += nw * 64) {
        const unsigned i = base + lane;
        u64 e = 0;
        bool keep = false;
        if (i < total) {
            e = cand[i];
            const int p = (int)(e >> 46);
            keep = (s2f((unsigned)(e & 0xffffffffull)) >= s2f(gmax[p]) - DELTA);
        }
        u64 mask = __ballot(keep);
        while (mask) {
            const int src = __ffsll((long long)mask) - 1;
            mask &= mask - 1;
            const unsigned pc = (unsigned)__shfl((int)(unsigned)(e >> 32), src);
            const int p = pc >> 14, c = pc & 16383;
            const float dinv = 1.0f / den[c];
            const float4 a = *(const float4*)(zf32 + (size_t)p * D + lane * 4);
            const float4 b = *(const float4*)(E + (size_t)c * D + lane * 4);
            float sv = fmaf(a.x, b.x * dinv, fmaf(a.y, b.y * dinv,
                       fmaf(a.z, b.z * dinv, a.w * (b.w * dinv))));
            #pragma unroll
            for (int o = 1; o < 64; o <<= 1) sv += __shfl_xor(sv, o);
            if (lane == 0)
                atomicMax(keys + p, ((u64)f2s(sv) << 32) | (unsigned)(16383 - c));
        }
    }
}

// ---- gather + outputs (LDS transpose for coalesced zq writes) ----
__global__ __launch_bounds__(256) void finalize(const float* __restrict__ E,
                                                const float* __restrict__ den,
                                                const u64* __restrict__ keys,
                                                float* __restrict__ out) {
    __shared__ float t[32][257];
    __shared__ int sIdx[32];
    __shared__ float sDen[32];
    const int tid = threadIdx.x;
    const int n0 = blockIdx.x * 32;
    if (tid < 32) {
        const u64 key = keys[n0 + tid];
        const int idx = 16383 - (int)(unsigned)(key & 0xffffffffull);
        sIdx[tid] = idx;
        sDen[tid] = den[idx];
        out[O_IDX + n0 + tid] = (float)idx;
    }
    __syncthreads();
    const float S = 5.65685424949238019520675489683895f;  // sqrt(32)
    #pragma unroll 4
    for (int i = 0; i < 32; ++i) {
        const float v = E[(size_t)sIdx[i] * D + tid] / sDen[i];
        t[i][tid] = v;
        out[O_BIT + (size_t)(n0 + i) * D + tid] = (float)((int)(v * S) + 4);
    }
    __syncthreads();
    const int b = n0 >> 10, hw0 = n0 & 1023;
    const int hwl = tid & 31, cg = tid >> 5;
    #pragma unroll 4
    for (int cc = 0; cc < 32; ++cc) {
        const int c = cc * 8 + cg;
        out[(size_t)(b * 256 + c) * 1024 + hw0 + hwl] = t[hwl][c];
    }
    if (n0 == 0 && tid == 0) out[O_LOSS] = 0.0f;
}

extern "C" void kernel_launch(void* const* d_in, const int* in_sizes, int n_in,
                              void* d_out, int out_size, void* d_ws, size_t ws_size,
                              hipStream_t stream) {
    const float* z = (const float*)d_in[0];
    const float* E = (const float*)d_in[1];
    float* out = (float*)d_out;

    char* w = (char*)d_ws;
    unsigned short* ewbT = (unsigned short*)w;  w += (size_t)K * D * 2;      //  8 MB
    unsigned short* zfbT = (unsigned short*)w;  w += (size_t)NPTS * D * 2;   //  4 MB
    float*          zf32 = (float*)w;           w += (size_t)NPTS * D * 4;   //  8 MB
    u64*            keys = (u64*)w;             w += (size_t)NPTS * 8;       // 64 KB
    float*          den  = (float*)w;           w += (size_t)K * 4;          // 64 KB
    unsigned*       gmax = (unsigned*)w;        w += (size_t)NPTS * 4;       // 32 KB
    unsigned*       cnt  = (unsigned*)w;        w += 256;
    u64*            cand = (u64*)w;             // remainder of ws
    const size_t fixed = (size_t)(w - (char*)d_ws);
    const size_t avail = ws_size > fixed ? (ws_size - fixed) / 8 : 0;
    const unsigned cap = (unsigned)(avail < (size_t)MAXCAP ? avail : (size_t)MAXCAP);

    prep<<<640, 256, 0, stream>>>(E, z, den, ewbT, zfbT, zf32, gmax, keys, cnt);

    score_seed<<<256, 512, 0, stream>>>(zfbT, ewbT, gmax, cand, cnt, cap);
    score_main<<<1792, 512, 0, stream>>>(zfbT, ewbT, gmax, cand, cnt, cap);

    cand_max<<<256, 256, 0, stream>>>(cand, cnt, gmax, cap);
    rescore<<<1024, 256, 0, stream>>>(zf32, E, den, gmax, cand, cnt, keys, cap);
    finalize<<<NPTS / 32, 256, 0, stream>>>(E, den, keys, out);
}

// Round 6
// 233.054 us; speedup vs baseline: 2.5253x; 1.0062x over previous
//
#include <hip/hip_runtime.h>
#include <math.h>

#define D      256
#define K      16384
#define NPTS   8192
#define DELTA  0.2f
#define LCAP   2048
#define MAXCAP 4000000u

// d_out layout (all f32): zq[8,256,32,32] | indices[8192] | bit[8,32,32,256] | loss[1]
#define O_IDX  2097152
#define O_BIT  2105344
#define O_LOSS 4202496

typedef __attribute__((ext_vector_type(8))) short bf16x8;
typedef __attribute__((ext_vector_type(4))) float f32x4;
typedef unsigned long long u64;

__device__ __forceinline__ unsigned f2s(float f) {
    unsigned u = __float_as_uint(f);
    return (u & 0x80000000u) ? ~u : (u | 0x80000000u);
}
__device__ __forceinline__ float s2f(unsigned s) {
    return __uint_as_float((s & 0x80000000u) ? (s & 0x7fffffffu) : ~s);
}
__device__ __forceinline__ unsigned short f2bf(float f) {  // RNE
    unsigned u = __float_as_uint(f);
    u += 0x7fffu + ((u >> 16) & 1u);
    return (unsigned short)(u >> 16);
}

// async global->LDS, 16B per lane (wave-uniform base + lane*16 dest)
__device__ __forceinline__ void gload16(const unsigned short* g, unsigned short* l) {
    __builtin_amdgcn_global_load_lds(
        (const __attribute__((address_space(1))) unsigned int*)g,
        (__attribute__((address_space(3))) unsigned int*)l, 16, 0, 0);
}

// generic LDS pointer -> 32-bit LDS byte offset for inline-asm ds_read
__device__ __forceinline__ unsigned lds_off(const void* p) {
    return (unsigned)(size_t)(const __attribute__((address_space(3))) void*)p;
}

// k-major fragment layouts: X[(k>>3)][row][8] bf16, 16B per (row, k-chunk)
//   zfbT: [32][NPTS][8] bf16 ; ewbT: [32][K][8] bf16

// ---- merged prep: blocks [0,512) codebook; [512,640) z transpose; state init folded ----
__global__ __launch_bounds__(256) void prep(const float* __restrict__ E,
                                            const float* __restrict__ z,
                                            float* __restrict__ den,
                                            unsigned short* __restrict__ ewbT,
                                            unsigned short* __restrict__ zfbT,
                                            float* __restrict__ zf32,
                                            unsigned* __restrict__ gmax,
                                            u64* __restrict__ keys,
                                            unsigned* __restrict__ cnt) {
    const int blk = blockIdx.x, tid = threadIdx.x;
    if (blk < 512) {
        const int lane = tid & 63, wave = tid >> 6;
        if (blk < 32)        gmax[blk * 256 + tid] = 0u;
        else if (blk < 64)   keys[(blk - 32) * 256 + tid] = 0ull;
        else if (blk == 64 && tid < 2) cnt[tid] = 0u;
        #pragma unroll
        for (int j = 0; j < 8; ++j) {
            const int row = blk * 32 + wave * 8 + j;
            const float4 v = *(const float4*)(E + (size_t)row * D + lane * 4);
            float ss = v.x * v.x + v.y * v.y + v.z * v.z + v.w * v.w;
            #pragma unroll
            for (int o = 1; o < 64; o <<= 1) ss += __shfl_xor(ss, o);
            const float dn = fmaxf(sqrtf(ss), 1e-12f);
            const unsigned lo = (unsigned)f2bf(v.x / dn) | ((unsigned)f2bf(v.y / dn) << 16);
            const unsigned hi = (unsigned)f2bf(v.z / dn) | ((unsigned)f2bf(v.w / dn) << 16);
            // k = lane*4 .. +4 -> chunk lane>>1, offset (lane&1)*4
            *(uint2*)(ewbT + ((size_t)(lane >> 1) * K + row) * 8 + (lane & 1) * 4)
                = make_uint2(lo, hi);
            if (lane == 0) den[row] = dn;
        }
    } else {
        const int bi = blk - 512;
        const int b = bi >> 4, hw0 = (bi & 15) * 64;
        __shared__ float t[64][65];
        for (int dc = 0; dc < D; dc += 64) {
            #pragma unroll
            for (int it = 0; it < 16; ++it) {
                const int idx = it * 256 + tid;
                const int dl = idx >> 6, hw = idx & 63;
                t[dl][hw] = z[(size_t)(b * 256 + dc + dl) * 1024 + hw0 + hw];
            }
            __syncthreads();
            #pragma unroll
            for (int it = 0; it < 16; ++it) {
                const int idx = it * 256 + tid;
                const int pl = idx >> 6, dl = idx & 63;
                const float v = t[dl][pl];
                const int p = b * 1024 + hw0 + pl, k = dc + dl;
                zfbT[((size_t)(k >> 3) * NPTS + p) * 8 + (k & 7)] = f2bf(v);
                zf32[(size_t)p * D + k] = v;
            }
            __syncthreads();
        }
    }
}

// ================= 256x256-tile pipelined GEMM core =================
// Round-6 change (single variable vs round 5): ALL core sync converted to canonical
// m201 form -- bare `asm volatile("s_waitcnt ...")` with NO ::: "memory" clobber,
// raw __builtin_amdgcn_s_barrier(), ordering pinned by sched_barrier(0) instead of
// clobbers. Theory: the "memory" clobbers made LLVM's waitcnt pass treat each asm as
// aliasing the outstanding global_load_lds queue and drain vmcnt(0) at every phase,
// silently re-creating the drain-per-step pathology inside all previous "counted"
// pipelines (all variants pinned at 19-22% MfmaUtil).
// Structure: 512 threads = 8 waves (2m x 4n), per-wave 128x64 (acc[8][4]), BK=64,
// 4 K-tiles, 2 LDS buffers, depth-2 counted vmcnt(8); only the last tile drains to 0.
// Ledger unchanged from round 5 (buf overwritten only after a barrier that every wave
// reaches with lgkmcnt(0) retired for all its reads of that buf; vmcnt FIFO per m135).

#define STAGE(buf, t)                                                               \
    do {                                                                            \
        const size_t oA_ = (size_t)(t) * (8u * NPTS * 8);                           \
        const size_t oB_ = (size_t)(t) * (8u * K * 8);                              \
        unsigned short* dA_ = &sA[buf][0][0][0];                                    \
        unsigned short* dB_ = &sB[buf][0][0][0];                                    \
        gload16(gA0_ + oA_, dA_ + (size_t)tid * 8);                                 \
        gload16(gA1_ + oA_, dA_ + (size_t)(512 + tid) * 8);                         \
        gload16(gA2_ + oA_, dA_ + (size_t)(1024 + tid) * 8);                        \
        gload16(gA3_ + oA_, dA_ + (size_t)(1536 + tid) * 8);                        \
        gload16(gB0_ + oB_, dB_ + (size_t)tid * 8);                                 \
        gload16(gB1_ + oB_, dB_ + (size_t)(512 + tid) * 8);                         \
        gload16(gB2_ + oB_, dB_ + (size_t)(1024 + tid) * 8);                        \
        gload16(gB3_ + oB_, dB_ + (size_t)(1536 + tid) * 8);                        \
        __builtin_amdgcn_sched_barrier(0);                                          \
    } while (0)

#define RKK(buf, AA, BB)                                                            \
    do {                                                                            \
        const unsigned a__ = (AA) + (unsigned)((buf) * 32768);                      \
        const unsigned b__ = (BB) + (unsigned)((buf) * 32768);                      \
        asm volatile("ds_read_b128 %0, %1"             : "=v"(af_[0]) : "v"(a__));  \
        asm volatile("ds_read_b128 %0, %1 offset:256"  : "=v"(af_[1]) : "v"(a__));  \
        asm volatile("ds_read_b128 %0, %1 offset:512"  : "=v"(af_[2]) : "v"(a__));  \
        asm volatile("ds_read_b128 %0, %1 offset:768"  : "=v"(af_[3]) : "v"(a__));  \
        asm volatile("ds_read_b128 %0, %1 offset:1024" : "=v"(af_[4]) : "v"(a__));  \
        asm volatile("ds_read_b128 %0, %1 offset:1280" : "=v"(af_[5]) : "v"(a__));  \
        asm volatile("ds_read_b128 %0, %1 offset:1536" : "=v"(af_[6]) : "v"(a__));  \
        asm volatile("ds_read_b128 %0, %1 offset:1792" : "=v"(af_[7]) : "v"(a__));  \
        asm volatile("ds_read_b128 %0, %1"             : "=v"(bf_[0]) : "v"(b__));  \
        asm volatile("ds_read_b128 %0, %1 offset:256"  : "=v"(bf_[1]) : "v"(b__));  \
        asm volatile("ds_read_b128 %0, %1 offset:512"  : "=v"(bf_[2]) : "v"(b__));  \
        asm volatile("ds_read_b128 %0, %1 offset:768"  : "=v"(bf_[3]) : "v"(b__));  \
    } while (0)

// rule #18: bare lgkmcnt(0) + sched_barrier(0) so MFMAs can't hoist above the wait
#define LGKM_SB                                                                     \
    asm volatile("s_waitcnt lgkmcnt(0)");                                           \
    __builtin_amdgcn_sched_barrier(0);

#define MFMAS                                                                       \
    do {                                                                            \
        __builtin_amdgcn_s_setprio(1);                                              \
        _Pragma("unroll")                                                           \
        for (int mt = 0; mt < 8; ++mt)                                              \
            _Pragma("unroll")                                                       \
            for (int nt = 0; nt < 4; ++nt)                                          \
                acc[mt][nt] = __builtin_amdgcn_mfma_f32_16x16x32_bf16(af_[mt], bf_[nt], \
                                                                      acc[mt][nt], 0, 0, 0); \
        __builtin_amdgcn_s_setprio(0);                                              \
    } while (0)

// counted vmcnt wait + raw barrier, no memory clobbers; sched_barrier pins order
#define WAITBAR(VM)                                                                 \
    __builtin_amdgcn_sched_barrier(0);                                              \
    asm volatile("s_waitcnt vmcnt(" VM ")");                                        \
    __builtin_amdgcn_s_barrier();                                                   \
    __builtin_amdgcn_sched_barrier(0);

#define MIDBAR                                                                      \
    __builtin_amdgcn_s_barrier();                                                   \
    __builtin_amdgcn_sched_barrier(0);

#define GEMM_CORE()                                                                 \
    __shared__ unsigned short sA[2][8][256][8];                                     \
    __shared__ unsigned short sB[2][8][256][8];                                     \
    f32x4 acc[8][4];                                                                \
    _Pragma("unroll")                                                               \
    for (int i_ = 0; i_ < 8; ++i_)                                                  \
        _Pragma("unroll")                                                           \
        for (int j_ = 0; j_ < 4; ++j_) acc[i_][j_] = (f32x4){0.f, 0.f, 0.f, 0.f};   \
    bf16x8 af_[8], bf_[4];                                                          \
    const int th_ = tid & 255, hi_ = tid >> 8;                                      \
    const int c0_ = hi_, c1_ = 2 + hi_, c2_ = 4 + hi_, c3_ = 6 + hi_;               \
    const unsigned short* gA0_ = zfbT + ((size_t)c0_ * NPTS + m0 + (th_ ^ (c0_ << 1))) * 8; \
    const unsigned short* gA1_ = zfbT + ((size_t)c1_ * NPTS + m0 + (th_ ^ (c1_ << 1))) * 8; \
    const unsigned short* gA2_ = zfbT + ((size_t)c2_ * NPTS + m0 + (th_ ^ (c2_ << 1))) * 8; \
    const unsigned short* gA3_ = zfbT + ((size_t)c3_ * NPTS + m0 + (th_ ^ (c3_ << 1))) * 8; \
    const unsigned short* gB0_ = ewbT + ((size_t)c0_ * K + n0 + (th_ ^ (c0_ << 1))) * 8; \
    const unsigned short* gB1_ = ewbT + ((size_t)c1_ * K + n0 + (th_ ^ (c1_ << 1))) * 8; \
    const unsigned short* gB2_ = ewbT + ((size_t)c2_ * K + n0 + (th_ ^ (c2_ << 1))) * 8; \
    const unsigned short* gB3_ = ewbT + ((size_t)c3_ * K + n0 + (th_ ^ (c3_ << 1))) * 8; \
    const unsigned sAb_ = lds_off(&sA[0][0][0][0]);                                 \
    const unsigned sBb_ = lds_off(&sB[0][0][0][0]);                                 \
    const int ck0_ = quad, ck1_ = 4 + quad;                                         \
    const unsigned aA0_ = sAb_ + (unsigned)((ck0_ * 256 + ((wm * 128 + col) ^ (ck0_ << 1))) * 16); \
    const unsigned aA1_ = sAb_ + (unsigned)((ck1_ * 256 + ((wm * 128 + col) ^ (ck1_ << 1))) * 16); \
    const unsigned bB0_ = sBb_ + (unsigned)((ck0_ * 256 + ((wn * 64 + col) ^ (ck0_ << 1))) * 16); \
    const unsigned bB1_ = sBb_ + (unsigned)((ck1_ * 256 + ((wn * 64 + col) ^ (ck1_ << 1))) * 16); \
    STAGE(0, 0);                                                                    \
    STAGE(1, 1);                                                                    \
    WAITBAR("8")                                                                    \
    RKK(0, aA0_, bB0_); LGKM_SB; MFMAS;                                             \
    RKK(0, aA1_, bB1_); LGKM_SB; MIDBAR; STAGE(0, 2); MFMAS;                        \
    WAITBAR("8")                                                                    \
    RKK(1, aA0_, bB0_); LGKM_SB; MFMAS;                                             \
    RKK(1, aA1_, bB1_); LGKM_SB; MIDBAR; STAGE(1, 3); MFMAS;                        \
    WAITBAR("8")                                                                    \
    RKK(0, aA0_, bB0_); LGKM_SB; MFMAS;                                             \
    RKK(0, aA1_, bB1_); LGKM_SB; MFMAS;                                             \
    WAITBAR("0")                                                                    \
    RKK(1, aA0_, bB0_); LGKM_SB; MFMAS;                                             \
    RKK(1, aA1_, bB1_); LGKM_SB; MFMAS;

// wave-aggregated global overflow append: one atomic per wave per batch (round-3 lesson:
// per-candidate same-address atomics serialize catastrophically)
#define CAND_APPEND(e)                                                              \
    do {                                                                            \
        const u64 am_ = __builtin_amdgcn_read_exec();                               \
        const unsigned n_ = (unsigned)__popcll(am_);                                \
        const unsigned rk_ = (unsigned)__popcll(am_ & ((1ull << lane) - 1));        \
        unsigned base_ = 0;                                                         \
        if (rk_ == 0) base_ = atomicAdd(cnt, n_);                                   \
        base_ = (unsigned)__builtin_amdgcn_readfirstlane((int)base_);               \
        const unsigned g_ = base_ + rk_;                                            \
        if (g_ < cap) cand[g_] = (e);                                               \
    } while (0)

// XCD-chunked bijective decode (1-D grid, xcd = bid & 7). XCD k owns mtiles [4k, 4k+4):
// per-XCD A footprint 4 x 131KB = 524KB L2-resident; n-tiles walked slowly.
#define XCD_DECODE(NT0)                                                             \
    const unsigned bid_ = blockIdx.x;                                               \
    const unsigned j_ = bid_ >> 3;                                                  \
    const int m0 = (int)(((bid_ & 7u) << 2) | (j_ & 3u)) * 256;                     \
    const int n0 = (NT0) + (int)(j_ >> 2) * 256;

// ---- phase 1: codes [0,2048). Self-seeded thresholds; publishes block max at exit. ----
__global__ __launch_bounds__(512, 2) void score_seed(const unsigned short* __restrict__ zfbT,
                                                     const unsigned short* __restrict__ ewbT,
                                                     unsigned* __restrict__ gmax,
                                                     u64* __restrict__ cand,
                                                     unsigned* __restrict__ cnt,
                                                     unsigned cap) {
    __shared__ unsigned thrS[256];
    __shared__ u64 lbuf[LCAP];
    __shared__ unsigned lcount, lbase;

    const int tid = threadIdx.x, lane = tid & 63, wave = tid >> 6;
    const int quad = lane >> 4, col = lane & 15;
    const int wm = wave >> 2, wn = wave & 3;
    XCD_DECODE(0)
    const int shsrc = lane & 48;

    if (tid < 256) thrS[tid] = 0u;
    if (tid == 0) lcount = 0u;

    GEMM_CORE()
    __syncthreads();   // all waves done with GEMM; publish thrS/lcount init before epilogue

    float red[8][4];
    #pragma unroll
    for (int mt = 0; mt < 8; ++mt)
        #pragma unroll
        for (int r = 0; r < 4; ++r)
            red[mt][r] = fmaxf(fmaxf(acc[mt][0][r], acc[mt][1][r]),
                               fmaxf(acc[mt][2][r], acc[mt][3][r]));
    #pragma unroll
    for (int off = 1; off < 16; off <<= 1)
        #pragma unroll
        for (int mt = 0; mt < 8; ++mt)
            #pragma unroll
            for (int r = 0; r < 4; ++r)
                red[mt][r] = fmaxf(red[mt][r], __shfl_xor(red[mt][r], off));
    #pragma unroll
    for (int mt = 0; mt < 8; ++mt)
        #pragma unroll
        for (int r = 0; r < 4; ++r) {
            const int pl = wm * 128 + mt * 16 + quad * 4 + r;
            unsigned cur = 0;
            if (col == 0) {
                const unsigned enc = f2s(red[mt][r]);
                const unsigned old = atomicMax(&thrS[pl], enc);
                cur = old > enc ? old : enc;
            }
            cur = (unsigned)__shfl((int)cur, shsrc);
            red[mt][r] = s2f(cur) - DELTA;
        }

    const int ncode0 = n0 + wn * 64 + col;
    #pragma unroll
    for (int mt = 0; mt < 8; ++mt) {
        #pragma unroll
        for (int r = 0; r < 4; ++r) {
            const float tp = red[mt][r];
            const unsigned pt = m0 + wm * 128 + mt * 16 + quad * 4 + r;
            #pragma unroll
            for (int nt = 0; nt < 4; ++nt) {
                const float v = acc[mt][nt][r];
                if (v >= tp) {
                    const unsigned slot = atomicAdd(&lcount, 1u);
                    const u64 e = ((u64)((pt << 14) | (unsigned)(ncode0 + nt * 16)) << 32)
                                  | f2s(v);
                    if (slot < LCAP) lbuf[slot] = e;
                    else CAND_APPEND(e);
                }
            }
        }
    }

    __syncthreads();
    if (tid < 256) atomicMax(&gmax[m0 + tid], thrS[tid]);
    const unsigned m_ = lcount < LCAP ? lcount : LCAP;
    if (tid == 0) lbase = atomicAdd(cnt, m_);
    __syncthreads();
    for (unsigned i = tid; i < m_; i += 512) {
        const unsigned g = lbase + i;
        if (g < cap) cand[g] = lbuf[i];
    }
}

// ---- phase 2: codes [2048,16384). Static thresholds from gmax. ----
__global__ __launch_bounds__(512, 2) void score_main(const unsigned short* __restrict__ zfbT,
                                                     const unsigned short* __restrict__ ewbT,
                                                     const unsigned* __restrict__ gmax,
                                                     u64* __restrict__ cand,
                                                     unsigned* __restrict__ cnt,
                                                     unsigned cap) {
    __shared__ float thrL[256];
    __shared__ u64 lbuf[LCAP];
    __shared__ unsigned lcount, lbase;

    const int tid = threadIdx.x, lane = tid & 63, wave = tid >> 6;
    const int quad = lane >> 4, col = lane & 15;
    const int wm = wave >> 2, wn = wave & 3;
    XCD_DECODE(2048)

    if (tid < 256) thrL[tid] = s2f(gmax[m0 + tid]) - DELTA;
    if (tid == 0) lcount = 0u;

    GEMM_CORE()
    __syncthreads();   // all waves done with GEMM; publish thrL/lcount init before epilogue

    const int ncode0 = n0 + wn * 64 + col;
    #pragma unroll
    for (int mt = 0; mt < 8; ++mt) {
        #pragma unroll
        for (int r = 0; r < 4; ++r) {
            const int pl = wm * 128 + mt * 16 + quad * 4 + r;
            const float tp = thrL[pl];
            #pragma unroll
            for (int nt = 0; nt < 4; ++nt) {
                const float v = acc[mt][nt][r];
                if (v >= tp) {
                    const unsigned slot = atomicAdd(&lcount, 1u);
                    const u64 e = ((u64)(((unsigned)pl + m0) << 14 | (unsigned)(ncode0 + nt * 16)) << 32)
                                  | f2s(v);
                    if (slot < LCAP) lbuf[slot] = e;
                    else CAND_APPEND(e);
                }
            }
        }
    }

    __syncthreads();
    const unsigned m_ = lcount < LCAP ? lcount : LCAP;
    if (tid == 0) lbase = atomicAdd(cnt, m_);
    __syncthreads();
    for (unsigned i = tid; i < m_; i += 512) {
        const unsigned g = lbase + i;
        if (g < cap) cand[g] = lbuf[i];
    }
}

// ---- final per-point bf16 max over candidates ----
__global__ __launch_bounds__(256) void cand_max(const u64* __restrict__ cand,
                                                const unsigned* __restrict__ cnt,
                                                unsigned* __restrict__ gmax,
                                                unsigned cap) {
    const unsigned total = min(cnt[0], cap);
    const unsigned stride = gridDim.x * 256;
    for (unsigned i = blockIdx.x * 256 + threadIdx.x; i < total; i += stride) {
        const u64 e = cand[i];
        atomicMax(&gmax[(unsigned)(e >> 46)], (unsigned)(e & 0xffffffffull));
    }
}

// ---- lane-parallel filter + ballot-compacted wave-cooperative fp32 rescore ----
__global__ __launch_bounds__(256) void rescore(const float* __restrict__ zf32,
                                               const float* __restrict__ E,
                                               const float* __restrict__ den,
                                               const unsigned* __restrict__ gmax,
                                               const u64* __restrict__ cand,
                                               const unsigned* __restrict__ cnt,
                                               u64* __restrict__ keys,
                                               unsigned cap) {
    const unsigned total = min(cnt[0], cap);
    const int lane = threadIdx.x & 63;
    const unsigned w = (blockIdx.x * 256 + threadIdx.x) >> 6;
    const unsigned nw = gridDim.x * 4;
    for (unsigned base = w * 64; base < total; base += nw * 64) {
        const unsigned i = base + lane;
        u64 e = 0;
        bool keep = false;
        if (i < total) {
            e = cand[i];
            const int p = (int)(e >> 46);
            keep = (s2f((unsigned)(e & 0xffffffffull)) >= s2f(gmax[p]) - DELTA);
        }
        u64 mask = __ballot(keep);
        while (mask) {
            const int src = __ffsll((long long)mask) - 1;
            mask &= mask - 1;
            const unsigned pc = (unsigned)__shfl((int)(unsigned)(e >> 32), src);
            const int p = pc >> 14, c = pc & 16383;
            const float dinv = 1.0f / den[c];
            const float4 a = *(const float4*)(zf32 + (size_t)p * D + lane * 4);
            const float4 b = *(const float4*)(E + (size_t)c * D + lane * 4);
            float sv = fmaf(a.x, b.x * dinv, fmaf(a.y, b.y * dinv,
                       fmaf(a.z, b.z * dinv, a.w * (b.w * dinv))));
            #pragma unroll
            for (int o = 1; o < 64; o <<= 1) sv += __shfl_xor(sv, o);
            if (lane == 0)
                atomicMax(keys + p, ((u64)f2s(sv) << 32) | (unsigned)(16383 - c));
        }
    }
}

// ---- gather + outputs (LDS transpose for coalesced zq writes) ----
__global__ __launch_bounds__(256) void finalize(const float* __restrict__ E,
                                                const float* __restrict__ den,
                                                const u64* __restrict__ keys,
                                                float* __restrict__ out) {
    __shared__ float t[32][257];
    __shared__ int sIdx[32];
    __shared__ float sDen[32];
    const int tid = threadIdx.x;
    const int n0 = blockIdx.x * 32;
    if (tid < 32) {
        const u64 key = keys[n0 + tid];
        const int idx = 16383 - (int)(unsigned)(key & 0xffffffffull);
        sIdx[tid] = idx;
        sDen[tid] = den[idx];
        out[O_IDX + n0 + tid] = (float)idx;
    }
    __syncthreads();
    const float S = 5.65685424949238019520675489683895f;  // sqrt(32)
    #pragma unroll 4
    for (int i = 0; i < 32; ++i) {
        const float v = E[(size_t)sIdx[i] * D + tid] / sDen[i];
        t[i][tid] = v;
        out[O_BIT + (size_t)(n0 + i) * D + tid] = (float)((int)(v * S) + 4);
    }
    __syncthreads();
    const int b = n0 >> 10, hw0 = n0 & 1023;
    const int hwl = tid & 31, cg = tid >> 5;
    #pragma unroll 4
    for (int cc = 0; cc < 32; ++cc) {
        const int c = cc * 8 + cg;
        out[(size_t)(b * 256 + c) * 1024 + hw0 + hwl] = t[hwl][c];
    }
    if (n0 == 0 && tid == 0) out[O_LOSS] = 0.0f;
}

extern "C" void kernel_launch(void* const* d_in, const int* in_sizes, int n_in,
                              void* d_out, int out_size, void* d_ws, size_t ws_size,
                              hipStream_t stream) {
    const float* z = (const float*)d_in[0];
    const float* E = (const float*)d_in[1];
    float* out = (float*)d_out;

    char* w = (char*)d_ws;
    unsigned short* ewbT = (unsigned short*)w;  w += (size_t)K * D * 2;      //  8 MB
    unsigned short* zfbT = (unsigned short*)w;  w += (size_t)NPTS * D * 2;   //  4 MB
    float*          zf32 = (float*)w;           w += (size_t)NPTS * D * 4;   //  8 MB
    u64*            keys = (u64*)w;             w += (size_t)NPTS * 8;       // 64 KB
    float*          den  = (float*)w;           w += (size_t)K * 4;          // 64 KB
    unsigned*       gmax = (unsigned*)w;        w += (size_t)NPTS * 4;       // 32 KB
    unsigned*       cnt  = (unsigned*)w;        w += 256;
    u64*            cand = (u64*)w;             // remainder of ws
    const size_t fixed = (size_t)(w - (char*)d_ws);
    const size_t avail = ws_size > fixed ? (ws_size - fixed) / 8 : 0;
    const unsigned cap = (unsigned)(avail < (size_t)MAXCAP ? avail : (size_t)MAXCAP);

    prep<<<640, 256, 0, stream>>>(E, z, den, ewbT, zfbT, zf32, gmax, keys, cnt);

    score_seed<<<256, 512, 0, stream>>>(zfbT, ewbT, gmax, cand, cnt, cap);
    score_main<<<1792, 512, 0, stream>>>(zfbT, ewbT, gmax, cand, cnt, cap);

    cand_max<<<256, 256, 0, stream>>>(cand, cnt, gmax, cap);
    rescore<<<1024, 256, 0, stream>>>(zf32, E, den, gmax, cand, cnt, keys, cap);
    finalize<<<NPTS / 32, 256, 0, stream>>>(E, den, keys, out);
}

// Round 7
// 232.945 us; speedup vs baseline: 2.5265x; 1.0005x over previous
//
#include <hip/hip_runtime.h>
#include <math.h>

#define D      256
#define K      16384
#define NPTS   8192
#define DELTA  0.2f
#define LCAP   2048
#define MAXCAP 4000000u

// d_out layout (all f32): zq[8,256,32,32] | indices[8192] | bit[8,32,32,256] | loss[1]
#define O_IDX  2097152
#define O_BIT  2105344
#define O_LOSS 4202496

typedef __attribute__((ext_vector_type(8))) short bf16x8;
typedef __attribute__((ext_vector_type(4))) float f32x4;
typedef unsigned long long u64;

__device__ __forceinline__ unsigned f2s(float f) {
    unsigned u = __float_as_uint(f);
    return (u & 0x80000000u) ? ~u : (u | 0x80000000u);
}
__device__ __forceinline__ float s2f(unsigned s) {
    return __uint_as_float((s & 0x80000000u) ? (s & 0x7fffffffu) : ~s);
}
__device__ __forceinline__ unsigned short f2bf(float f) {  // RNE
    unsigned u = __float_as_uint(f);
    u += 0x7fffu + ((u >> 16) & 1u);
    return (unsigned short)(u >> 16);
}

// async global->LDS, 16B per lane (wave-uniform base + lane*16 dest)
__device__ __forceinline__ void gload16(const unsigned short* g, unsigned short* l) {
    __builtin_amdgcn_global_load_lds(
        (const __attribute__((address_space(1))) unsigned int*)g,
        (__attribute__((address_space(3))) unsigned int*)l, 16, 0, 0);
}

// generic LDS pointer -> 32-bit LDS byte offset for inline-asm ds_read
__device__ __forceinline__ unsigned lds_off(const void* p) {
    return (unsigned)(size_t)(const __attribute__((address_space(3))) void*)p;
}

// k-major fragment layouts: X[(k>>3)][row][8] bf16, 16B per (row, k-chunk)
//   zfbT: [32][NPTS][8] bf16 ; ewbT: [32][K][8] bf16

// ---- merged prep: blocks [0,512) codebook; [512,640) z transpose; state init folded ----
__global__ __launch_bounds__(256) void prep(const float* __restrict__ E,
                                            const float* __restrict__ z,
                                            float* __restrict__ den,
                                            unsigned short* __restrict__ ewbT,
                                            unsigned short* __restrict__ zfbT,
                                            float* __restrict__ zf32,
                                            unsigned* __restrict__ gmax,
                                            u64* __restrict__ keys,
                                            unsigned* __restrict__ cnt) {
    const int blk = blockIdx.x, tid = threadIdx.x;
    if (blk < 512) {
        const int lane = tid & 63, wave = tid >> 6;
        if (blk < 32)        gmax[blk * 256 + tid] = 0u;
        else if (blk < 64)   keys[(blk - 32) * 256 + tid] = 0ull;
        else if (blk == 64 && tid < 2) cnt[tid] = 0u;
        #pragma unroll
        for (int j = 0; j < 8; ++j) {
            const int row = blk * 32 + wave * 8 + j;
            const float4 v = *(const float4*)(E + (size_t)row * D + lane * 4);
            float ss = v.x * v.x + v.y * v.y + v.z * v.z + v.w * v.w;
            #pragma unroll
            for (int o = 1; o < 64; o <<= 1) ss += __shfl_xor(ss, o);
            const float dn = fmaxf(sqrtf(ss), 1e-12f);
            const unsigned lo = (unsigned)f2bf(v.x / dn) | ((unsigned)f2bf(v.y / dn) << 16);
            const unsigned hi = (unsigned)f2bf(v.z / dn) | ((unsigned)f2bf(v.w / dn) << 16);
            // k = lane*4 .. +4 -> chunk lane>>1, offset (lane&1)*4
            *(uint2*)(ewbT + ((size_t)(lane >> 1) * K + row) * 8 + (lane & 1) * 4)
                = make_uint2(lo, hi);
            if (lane == 0) den[row] = dn;
        }
    } else {
        const int bi = blk - 512;
        const int b = bi >> 4, hw0 = (bi & 15) * 64;
        __shared__ float t[64][65];
        for (int dc = 0; dc < D; dc += 64) {
            #pragma unroll
            for (int it = 0; it < 16; ++it) {
                const int idx = it * 256 + tid;
                const int dl = idx >> 6, hw = idx & 63;
                t[dl][hw] = z[(size_t)(b * 256 + dc + dl) * 1024 + hw0 + hw];
            }
            __syncthreads();
            #pragma unroll
            for (int it = 0; it < 16; ++it) {
                const int idx = it * 256 + tid;
                const int pl = idx >> 6, dl = idx & 63;
                const float v = t[dl][pl];
                const int p = b * 1024 + hw0 + pl, k = dc + dl;
                zfbT[((size_t)(k >> 3) * NPTS + p) * 8 + (k & 7)] = f2bf(v);
                zf32[(size_t)p * D + k] = v;
            }
            __syncthreads();
        }
    }
}

// ================= 256x256 8-phase GEMM core (m201-structure port) =================
// 512 threads = 8 waves (2m x 4n), per-wave 128x64 (acc[8][4]), BK=64, 4 K-tiles,
// 4 fine phases per K-tile (16 total). Phase = { 4-8 asm ds_read (one kk-half x m-group,
// bf reused across the m-group pair), 2 global_load_lds (one half-unit of tile t+1),
// s_barrier, lgkmcnt(0)+sched_barrier (rule #18), setprio(1), 16 MFMA, setprio(0),
// [vmcnt(4) at K-half boundaries -- BEFORE the closing barrier so the barrier converts
// my-wave load retirement into all-waves retirement], s_barrier }.
// vmcnt never drains to 0 until the last tile (counted: 4 loads = the not-yet-needed
// half-tile stay in flight). Ledger: slot s's kk-region rewritten (staging tile t+2,
// during t+1) only after t's ph3 closing barrier, which every wave reaches post-lgkm(0)
// of all its reads of slot s. Reads of (t,kkX) occur after a vmcnt(4)+barrier pair that
// proves all waves' (t,kkX) loads retired (FIFO retirement, m135).
// LDS cell order permuted on the GLOBAL side (source row th ^ (chunk<<1)) so fragment
// ds_read_b128s keep the measured-zero bank-conflict pattern; reads undo the XOR.

#define SBAR  __builtin_amdgcn_sched_barrier(0);
#define BARR  __builtin_amdgcn_s_barrier();
#define VMC(N) asm volatile("s_waitcnt vmcnt(" N ")");
#define LGKM_SB  asm volatile("s_waitcnt lgkmcnt(0)"); __builtin_amdgcn_sched_barrier(0);

#define STG_A(slot, t, kk)                                                          \
    do {                                                                            \
        const int cA1_ = (kk) * 4 + hi_, cA2_ = (kk) * 4 + 2 + hi_;                 \
        gload16(zfbT + ((size_t)((t) * 8 + cA1_) * NPTS + m0 + (th_ ^ (cA1_ << 1))) * 8, \
                &sA[slot][cA1_][th_][0]);                                           \
        gload16(zfbT + ((size_t)((t) * 8 + cA2_) * NPTS + m0 + (th_ ^ (cA2_ << 1))) * 8, \
                &sA[slot][cA2_][th_][0]);                                           \
    } while (0)

#define STG_B(slot, t, kk)                                                          \
    do {                                                                            \
        const int cB1_ = (kk) * 4 + hi_, cB2_ = (kk) * 4 + 2 + hi_;                 \
        gload16(ewbT + ((size_t)((t) * 8 + cB1_) * K + n0 + (th_ ^ (cB1_ << 1))) * 8, \
                &sB[slot][cB1_][th_][0]);                                           \
        gload16(ewbT + ((size_t)((t) * 8 + cB2_) * K + n0 + (th_ ^ (cB2_ << 1))) * 8, \
                &sB[slot][cB2_][th_][0]);                                           \
    } while (0)

#define RD_A(slot, kO, mg)                                                          \
    do {                                                                            \
        const unsigned a__ = sAb_ + (unsigned)((slot) * 32768 + (mg) * 1024) + (kO);\
        asm volatile("ds_read_b128 %0, %1"            : "=v"(af_[0]) : "v"(a__));   \
        asm volatile("ds_read_b128 %0, %1 offset:256" : "=v"(af_[1]) : "v"(a__));   \
        asm volatile("ds_read_b128 %0, %1 offset:512" : "=v"(af_[2]) : "v"(a__));   \
        asm volatile("ds_read_b128 %0, %1 offset:768" : "=v"(af_[3]) : "v"(a__));   \
    } while (0)

#define RD_B(slot, kO)                                                              \
    do {                                                                            \
        const unsigned b__ = sBb_ + (unsigned)((slot) * 32768) + (kO);              \
        asm volatile("ds_read_b128 %0, %1"            : "=v"(bf_[0]) : "v"(b__));   \
        asm volatile("ds_read_b128 %0, %1 offset:256" : "=v"(bf_[1]) : "v"(b__));   \
        asm volatile("ds_read_b128 %0, %1 offset:512" : "=v"(bf_[2]) : "v"(b__));   \
        asm volatile("ds_read_b128 %0, %1 offset:768" : "=v"(bf_[3]) : "v"(b__));   \
    } while (0)

#define MF(mg)                                                                      \
    do {                                                                            \
        __builtin_amdgcn_s_setprio(1);                                              \
        _Pragma("unroll")                                                           \
        for (int j_ = 0; j_ < 4; ++j_)                                              \
            _Pragma("unroll")                                                       \
            for (int nt_ = 0; nt_ < 4; ++nt_)                                       \
                acc[(mg) * 4 + j_][nt_] = __builtin_amdgcn_mfma_f32_16x16x32_bf16(  \
                    af_[j_], bf_[nt_], acc[(mg) * 4 + j_][nt_], 0, 0, 0);           \
        __builtin_amdgcn_s_setprio(0);                                              \
    } while (0)

// one K-tile = 4 phases; V1 = vmcnt at K-half boundary (kk1 of this tile landed),
// V2 = vmcnt at tile boundary (next tile's kk0 landed). SA0..SB1 stage tile t+1 halves.
#define KTILE(slot, SA0, SB0, SA1, SB1, V1, V2)                                     \
    RD_A(slot, aOff0_, 0); RD_B(slot, bOff0_); SA0; SBAR BARR LGKM_SB MF(0); SBAR BARR SBAR \
    RD_A(slot, aOff0_, 1);                     SB0; SBAR BARR LGKM_SB MF(1); SBAR VMC(V1) BARR SBAR \
    RD_A(slot, aOff1_, 0); RD_B(slot, bOff1_); SA1; SBAR BARR LGKM_SB MF(0); SBAR BARR SBAR \
    RD_A(slot, aOff1_, 1);                     SB1; SBAR BARR LGKM_SB MF(1); SBAR V2 BARR SBAR

#define GEMM_CORE()                                                                 \
    __shared__ unsigned short sA[2][8][256][8];                                     \
    __shared__ unsigned short sB[2][8][256][8];                                     \
    f32x4 acc[8][4];                                                                \
    _Pragma("unroll")                                                               \
    for (int i_ = 0; i_ < 8; ++i_)                                                  \
        _Pragma("unroll")                                                           \
        for (int j_ = 0; j_ < 4; ++j_) acc[i_][j_] = (f32x4){0.f, 0.f, 0.f, 0.f};   \
    bf16x8 af_[4], bf_[4];                                                          \
    const int th_ = tid & 255, hi_ = tid >> 8;                                      \
    const int aRow_ = wm * 128 + col, bRow_ = wn * 64 + col;                        \
    const unsigned sAb_ = lds_off(&sA[0][0][0][0]);                                 \
    const unsigned sBb_ = lds_off(&sB[0][0][0][0]);                                 \
    const int ck0_ = quad, ck1_ = 4 + quad;                                         \
    const unsigned aOff0_ = (unsigned)((ck0_ * 256 + (aRow_ ^ (ck0_ << 1))) * 16);  \
    const unsigned aOff1_ = (unsigned)((ck1_ * 256 + (aRow_ ^ (ck1_ << 1))) * 16);  \
    const unsigned bOff0_ = (unsigned)((ck0_ * 256 + (bRow_ ^ (ck0_ << 1))) * 16);  \
    const unsigned bOff1_ = (unsigned)((ck1_ * 256 + (bRow_ ^ (ck1_ << 1))) * 16);  \
    STG_A(0, 0, 0); STG_B(0, 0, 0); STG_A(0, 0, 1); STG_B(0, 0, 1);                 \
    SBAR VMC("4") BARR SBAR                                                         \
    KTILE(0, STG_A(1, 1, 0), STG_B(1, 1, 0), STG_A(1, 1, 1), STG_B(1, 1, 1), "4", VMC("4")) \
    KTILE(1, STG_A(0, 2, 0), STG_B(0, 2, 0), STG_A(0, 2, 1), STG_B(0, 2, 1), "4", VMC("4")) \
    KTILE(0, STG_A(1, 3, 0), STG_B(1, 3, 0), STG_A(1, 3, 1), STG_B(1, 3, 1), "4", VMC("4")) \
    KTILE(1, , , , , "0", )

// wave-aggregated global overflow append: one atomic per wave per batch (round-3 lesson:
// per-candidate same-address atomics serialize catastrophically)
#define CAND_APPEND(e)                                                              \
    do {                                                                            \
        const u64 am_ = __builtin_amdgcn_read_exec();                               \
        const unsigned n_ = (unsigned)__popcll(am_);                                \
        const unsigned rk_ = (unsigned)__popcll(am_ & ((1ull << lane) - 1));        \
        unsigned base_ = 0;                                                         \
        if (rk_ == 0) base_ = atomicAdd(cnt, n_);                                   \
        base_ = (unsigned)__builtin_amdgcn_readfirstlane((int)base_);               \
        const unsigned g_ = base_ + rk_;                                            \
        if (g_ < cap) cand[g_] = (e);                                               \
    } while (0)

// XCD-chunked bijective decode (1-D grid, xcd = bid & 7). XCD k owns mtiles [4k, 4k+4):
// per-XCD A footprint 4 x 131KB = 524KB L2-resident; n-tiles walked slowly.
#define XCD_DECODE(NT0)                                                             \
    const unsigned bid_ = blockIdx.x;                                               \
    const unsigned j_ = bid_ >> 3;                                                  \
    const int m0 = (int)(((bid_ & 7u) << 2) | (j_ & 3u)) * 256;                     \
    const int n0 = (NT0) + (int)(j_ >> 2) * 256;

// ---- phase 1: codes [0,2048). Self-seeded thresholds; publishes block max at exit. ----
__global__ __launch_bounds__(512, 2) void score_seed(const unsigned short* __restrict__ zfbT,
                                                     const unsigned short* __restrict__ ewbT,
                                                     unsigned* __restrict__ gmax,
                                                     u64* __restrict__ cand,
                                                     unsigned* __restrict__ cnt,
                                                     unsigned cap) {
    __shared__ unsigned thrS[256];
    __shared__ u64 lbuf[LCAP];
    __shared__ unsigned lcount, lbase;

    const int tid = threadIdx.x, lane = tid & 63, wave = tid >> 6;
    const int quad = lane >> 4, col = lane & 15;
    const int wm = wave >> 2, wn = wave & 3;
    XCD_DECODE(0)
    const int shsrc = lane & 48;

    if (tid < 256) thrS[tid] = 0u;
    if (tid == 0) lcount = 0u;

    GEMM_CORE()
    __syncthreads();   // all waves done with GEMM; publish thrS/lcount init before epilogue

    float red[8][4];
    #pragma unroll
    for (int mt = 0; mt < 8; ++mt)
        #pragma unroll
        for (int r = 0; r < 4; ++r)
            red[mt][r] = fmaxf(fmaxf(acc[mt][0][r], acc[mt][1][r]),
                               fmaxf(acc[mt][2][r], acc[mt][3][r]));
    #pragma unroll
    for (int off = 1; off < 16; off <<= 1)
        #pragma unroll
        for (int mt = 0; mt < 8; ++mt)
            #pragma unroll
            for (int r = 0; r < 4; ++r)
                red[mt][r] = fmaxf(red[mt][r], __shfl_xor(red[mt][r], off));
    #pragma unroll
    for (int mt = 0; mt < 8; ++mt)
        #pragma unroll
        for (int r = 0; r < 4; ++r) {
            const int pl = wm * 128 + mt * 16 + quad * 4 + r;
            unsigned cur = 0;
            if (col == 0) {
                const unsigned enc = f2s(red[mt][r]);
                const unsigned old = atomicMax(&thrS[pl], enc);
                cur = old > enc ? old : enc;
            }
            cur = (unsigned)__shfl((int)cur, shsrc);
            red[mt][r] = s2f(cur) - DELTA;
        }

    const int ncode0 = n0 + wn * 64 + col;
    #pragma unroll
    for (int mt = 0; mt < 8; ++mt) {
        #pragma unroll
        for (int r = 0; r < 4; ++r) {
            const float tp = red[mt][r];
            const unsigned pt = m0 + wm * 128 + mt * 16 + quad * 4 + r;
            #pragma unroll
            for (int nt = 0; nt < 4; ++nt) {
                const float v = acc[mt][nt][r];
                if (v >= tp) {
                    const unsigned slot = atomicAdd(&lcount, 1u);
                    const u64 e = ((u64)((pt << 14) | (unsigned)(ncode0 + nt * 16)) << 32)
                                  | f2s(v);
                    if (slot < LCAP) lbuf[slot] = e;
                    else CAND_APPEND(e);
                }
            }
        }
    }

    __syncthreads();
    if (tid < 256) atomicMax(&gmax[m0 + tid], thrS[tid]);
    const unsigned m_ = lcount < LCAP ? lcount : LCAP;
    if (tid == 0) lbase = atomicAdd(cnt, m_);
    __syncthreads();
    for (unsigned i = tid; i < m_; i += 512) {
        const unsigned g = lbase + i;
        if (g < cap) cand[g] = lbuf[i];
    }
}

// ---- phase 2: codes [2048,16384). Static thresholds from gmax. ----
__global__ __launch_bounds__(512, 2) void score_main(const unsigned short* __restrict__ zfbT,
                                                     const unsigned short* __restrict__ ewbT,
                                                     const unsigned* __restrict__ gmax,
                                                     u64* __restrict__ cand,
                                                     unsigned* __restrict__ cnt,
                                                     unsigned cap) {
    __shared__ float thrL[256];
    __shared__ u64 lbuf[LCAP];
    __shared__ unsigned lcount, lbase;

    const int tid = threadIdx.x, lane = tid & 63, wave = tid >> 6;
    const int quad = lane >> 4, col = lane & 15;
    const int wm = wave >> 2, wn = wave & 3;
    XCD_DECODE(2048)

    if (tid < 256) thrL[tid] = s2f(gmax[m0 + tid]) - DELTA;
    if (tid == 0) lcount = 0u;

    GEMM_CORE()
    __syncthreads();   // all waves done with GEMM; publish thrL/lcount init before epilogue

    const int ncode0 = n0 + wn * 64 + col;
    #pragma unroll
    for (int mt = 0; mt < 8; ++mt) {
        #pragma unroll
        for (int r = 0; r < 4; ++r) {
            const int pl = wm * 128 + mt * 16 + quad * 4 + r;
            const float tp = thrL[pl];
            #pragma unroll
            for (int nt = 0; nt < 4; ++nt) {
                const float v = acc[mt][nt][r];
                if (v >= tp) {
                    const unsigned slot = atomicAdd(&lcount, 1u);
                    const u64 e = ((u64)(((unsigned)pl + m0) << 14 | (unsigned)(ncode0 + nt * 16)) << 32)
                                  | f2s(v);
                    if (slot < LCAP) lbuf[slot] = e;
                    else CAND_APPEND(e);
                }
            }
        }
    }

    __syncthreads();
    const unsigned m_ = lcount < LCAP ? lcount : LCAP;
    if (tid == 0) lbase = atomicAdd(cnt, m_);
    __syncthreads();
    for (unsigned i = tid; i < m_; i += 512) {
        const unsigned g = lbase + i;
        if (g < cap) cand[g] = lbuf[i];
    }
}

// ---- final per-point bf16 max over candidates ----
__global__ __launch_bounds__(256) void cand_max(const u64* __restrict__ cand,
                                                const unsigned* __restrict__ cnt,
                                                unsigned* __restrict__ gmax,
                                                unsigned cap) {
    const unsigned total = min(cnt[0], cap);
    const unsigned stride = gridDim.x * 256;
    for (unsigned i = blockIdx.x * 256 + threadIdx.x; i < total; i += stride) {
        const u64 e = cand[i];
        atomicMax(&gmax[(unsigned)(e >> 46)], (unsigned)(e & 0xffffffffull));
    }
}

// ---- lane-parallel filter + ballot-compacted wave-cooperative fp32 rescore ----
__global__ __launch_bounds__(256) void rescore(const float* __restrict__ zf32,
                                               const float* __restrict__ E,
                                               const float* __restrict__ den,
                                               const unsigned* __restrict__ gmax,
                                               const u64* __restrict__ cand,
                                               const unsigned* __restrict__ cnt,
                                               u64* __restrict__ keys,
                                               unsigned cap) {
    const unsigned total = min(cnt[0], cap);
    const int lane = threadIdx.x & 63;
    const unsigned w = (blockIdx.x * 256 + threadIdx.x) >> 6;
    const unsigned nw = gridDim.x * 4;
    for (unsigned base = w * 64; base < total; base += nw * 64) {
        const unsigned i = base + lane;
        u64 e = 0;
        bool keep = false;
        if (i < total) {
            e = cand[i];
            const int p = (int)(e >> 46);
            keep = (s2f((unsigned)(e & 0xffffffffull)) >= s2f(gmax[p]) - DELTA);
        }
        u64 mask = __ballot(keep);
        while (mask) {
            const int src = __ffsll((long long)mask) - 1;
            mask &= mask - 1;
            const unsigned pc = (unsigned)__shfl((int)(unsigned)(e >> 32), src);
            const int p = pc >> 14, c = pc & 16383;
            const float dinv = 1.0f / den[c];
            const float4 a = *(const float4*)(zf32 + (size_t)p * D + lane * 4);
            const float4 b = *(const float4*)(E + (size_t)c * D + lane * 4);
            float sv = fmaf(a.x, b.x * dinv, fmaf(a.y, b.y * dinv,
                       fmaf(a.z, b.z * dinv, a.w * (b.w * dinv))));
            #pragma unroll
            for (int o = 1; o < 64; o <<= 1) sv += __shfl_xor(sv, o);
            if (lane == 0)
                atomicMax(keys + p, ((u64)f2s(sv) << 32) | (unsigned)(16383 - c));
        }
    }
}

// ---- gather + outputs (LDS transpose for coalesced zq writes) ----
__global__ __launch_bounds__(256) void finalize(const float* __restrict__ E,
                                                const float* __restrict__ den,
                                                const u64* __restrict__ keys,
                                                float* __restrict__ out) {
    __shared__ float t[32][257];
    __shared__ int sIdx[32];
    __shared__ float sDen[32];
    const int tid = threadIdx.x;
    const int n0 = blockIdx.x * 32;
    if (tid < 32) {
        const u64 key = keys[n0 + tid];
        const int idx = 16383 - (int)(unsigned)(key & 0xffffffffull);
        sIdx[tid] = idx;
        sDen[tid] = den[idx];
        out[O_IDX + n0 + tid] = (float)idx;
    }
    __syncthreads();
    const float S = 5.65685424949238019520675489683895f;  // sqrt(32)
    #pragma unroll 4
    for (int i = 0; i < 32; ++i) {
        const float v = E[(size_t)sIdx[i] * D + tid] / sDen[i];
        t[i][tid] = v;
        out[O_BIT + (size_t)(n0 + i) * D + tid] = (float)((int)(v * S) + 4);
    }
    __syncthreads();
    const int b = n0 >> 10, hw0 = n0 & 1023;
    const int hwl = tid & 31, cg = tid >> 5;
    #pragma unroll 4
    for (int cc = 0; cc < 32; ++cc) {
        const int c = cc * 8 + cg;
        out[(size_t)(b * 256 + c) * 1024 + hw0 + hwl] = t[hwl][c];
    }
    if (n0 == 0 && tid == 0) out[O_LOSS] = 0.0f;
}

extern "C" void kernel_launch(void* const* d_in, const int* in_sizes, int n_in,
                              void* d_out, int out_size, void* d_ws, size_t ws_size,
                              hipStream_t stream) {
    const float* z = (const float*)d_in[0];
    const float* E = (const float*)d_in[1];
    float* out = (float*)d_out;

    char* w = (char*)d_ws;
    unsigned short* ewbT = (unsigned short*)w;  w += (size_t)K * D * 2;      //  8 MB
    unsigned short* zfbT = (unsigned short*)w;  w += (size_t)NPTS * D * 2;   //  4 MB
    float*          zf32 = (float*)w;           w += (size_t)NPTS * D * 4;   //  8 MB
    u64*            keys = (u64*)w;             w += (size_t)NPTS * 8;       // 64 KB
    float*          den  = (float*)w;           w += (size_t)K * 4;          // 64 KB
    unsigned*       gmax = (unsigned*)w;        w += (size_t)NPTS * 4;       // 32 KB
    unsigned*       cnt  = (unsigned*)w;        w += 256;
    u64*            cand = (u64*)w;             // remainder of ws
    const size_t fixed = (size_t)(w - (char*)d_ws);
    const size_t avail = ws_size > fixed ? (ws_size - fixed) / 8 : 0;
    const unsigned cap = (unsigned)(avail < (size_t)MAXCAP ? avail : (size_t)MAXCAP);

    prep<<<640, 256, 0, stream>>>(E, z, den, ewbT, zfbT, zf32, gmax, keys, cnt);

    score_seed<<<256, 512, 0, stream>>>(zfbT, ewbT, gmax, cand, cnt, cap);
    score_main<<<1792, 512, 0, stream>>>(zfbT, ewbT, gmax, cand, cnt, cap);

    cand_max<<<256, 256, 0, stream>>>(cand, cnt, gmax, cap);
    rescore<<<1024, 256, 0, stream>>>(zf32, E, den, gmax, cand, cnt, keys, cap);
    finalize<<<NPTS / 32, 256, 0, stream>>>(E, den, keys, out);
}